// Round 1
// baseline (2939.625 us; speedup 1.0000x reference)
//
#include <hip/hip_runtime.h>
#include <math.h>

// Problem dims
#define NB   64      // batch B
#define NN   256     // tokens N
#define HSS  768     // H_S
#define HTT  1024    // H_T
#define ROWS (NB*NN) // 16384

// ---------------- workspace layout (float offsets) ----------------
static const size_t OFF_ACC   = 0;                         // 16 floats accum
static const size_t OFF_SQ128 = 16;                        // 64*128
static const size_t OFF_SP128 = OFF_SQ128 + 64*128;        // contiguous -> s_batch
static const size_t OFF_TQ128 = OFF_SP128 + 64*128;
static const size_t OFF_TP128 = OFF_TQ128 + 64*128;        // contiguous -> t_batch
static const size_t OFF_SQ768 = OFF_TP128 + 64*128;
static const size_t OFF_SP768 = OFF_SQ768 + 64*768;
static const size_t OFF_DS    = OFF_SP768 + 64*768;        // 128*128
static const size_t OFF_DT    = OFF_DS + 128*128;
static const size_t OFF_PSI   = OFF_DT + 128*128;          // 128*16384 = 2M floats
static const size_t OFF_ZSP   = OFF_PSI + (size_t)128*16384;     // 16384*1024
static const size_t OFF_CS    = OFF_ZSP + (size_t)ROWS*HTT;      // B*N*N
static const size_t OFF_CT    = OFF_CS + (size_t)NB*NN*NN;
static const size_t OFF_M     = OFF_CT + (size_t)NB*NN*NN;
static const size_t OFF_GN    = OFF_M  + (size_t)NB*NN*NN;       // Mt, later Gamma_norm
static const size_t OFF_T     = OFF_GN + (size_t)NB*NN*NN;
static const size_t OFF_NS    = OFF_T  + (size_t)NB*NN*NN;       // row norms z_s
static const size_t OFF_NT    = OFF_NS + ROWS;
static const size_t OFF_NSP   = OFF_NT + ROWS;
static const size_t OFF_MU    = OFF_NSP + ROWS;
static const size_t OFF_NU    = OFF_MU + ROWS;
static const size_t OFF_LOGMU = OFF_NU + ROWS;
static const size_t OFF_LOGNU = OFF_LOGMU + ROWS;
static const size_t OFF_U     = OFF_LOGNU + ROWS;
static const size_t OFF_V     = OFF_U + ROWS;

// acc indices: 0=contrastive 1=ds_sum 2=dt_sum 3=dist_huber 4=angle_huber 5=feat 6=struct

// ---------------- reductions ----------------
__device__ __forceinline__ float wred_sum(float v){
  #pragma unroll
  for(int o=32;o>0;o>>=1) v += __shfl_xor(v,o,64);
  return v;
}
__device__ __forceinline__ float wred_max(float v){
  #pragma unroll
  for(int o=32;o>0;o>>=1) v = fmaxf(v, __shfl_xor(v,o,64));
  return v;
}

// ---------------- Part A kernels ----------------
// one block (256 thr) per row: out = row / max(||row||,1e-12), first k_use of k_in cols
__global__ __launch_bounds__(256) void k_l2norm_rows(const float* __restrict__ in,
    float* __restrict__ out, int k_in, int k_use){
  int r = blockIdx.x;
  const float* row = in + (size_t)r*k_in;
  float ss = 0.f;
  for(int d=threadIdx.x; d<k_use; d+=256){ float x=row[d]; ss += x*x; }
  ss = wred_sum(ss);
  __shared__ float sm[4];
  if((threadIdx.x&63)==0) sm[threadIdx.x>>6]=ss;
  __syncthreads();
  float tot = sm[0]+sm[1]+sm[2]+sm[3];
  float inv = 1.f / fmaxf(sqrtf(tot), 1e-12f);
  for(int d=threadIdx.x; d<k_use; d+=256) out[(size_t)r*k_use + d] = row[d]*inv;
}

// grid 64 blocks (row i), 64 threads (col j). scores=q·p^T/T, CE = mean(logZ - diag)
__global__ __launch_bounds__(64) void k_contrastive(const float* __restrict__ q,
    const float* __restrict__ p, int dim, float weight, float* __restrict__ acc){
  int i = blockIdx.x, j = threadIdx.x;
  const float* qi = q + (size_t)i*dim;
  const float* pj = p + (size_t)j*dim;
  float dot = 0.f;
  for(int d=0; d<dim; d++) dot += qi[d]*pj[d];
  float s = dot / 0.07f;
  float mx = wred_max(s);
  float e = expf(s - mx);
  float Z = wred_sum(e);
  float logZ = mx + logf(Z);
  float diag = __shfl(s, i, 64);
  if(j==0) atomicAdd(acc+0, weight*(logZ - diag)*(1.f/64.f));
}

// grid 128 (r), 128 thr (c): ds/dt pairwise sq-dists + masked sums (upper tri)
__global__ __launch_bounds__(128) void k_gram_ds(const float* __restrict__ sb,
    const float* __restrict__ tb, float* __restrict__ ds, float* __restrict__ dt,
    float* __restrict__ acc){
  int r = blockIdx.x, c = threadIdx.x;
  const float* sr = sb + r*128; const float* sc = sb + c*128;
  const float* tr = tb + r*128; const float* tc = tb + c*128;
  float dot_s=0,ssr=0,ssc=0,dot_t=0,tsr=0,tsc=0;
  for(int d=0; d<128; d++){
    float a=sr[d], b=sc[d]; dot_s += a*b; ssr += a*a; ssc += b*b;
    float at=tr[d], bt=tc[d]; dot_t += at*bt; tsr += at*at; tsc += bt*bt;
  }
  float dv = ssr + ssc - 2.f*dot_s;
  float tv = tsr + tsc - 2.f*dot_t;
  ds[r*128+c] = dv; dt[r*128+c] = tv;
  float ms = (c>r)? dv : 0.f;
  float mt = (c>r)? tv : 0.f;
  ms = wred_sum(ms); mt = wred_sum(mt);
  __shared__ float sm[2][2];
  if((threadIdx.x&63)==0){ sm[0][threadIdx.x>>6]=ms; sm[1][threadIdx.x>>6]=mt; }
  __syncthreads();
  if(threadIdx.x==0){ atomicAdd(acc+1, sm[0][0]+sm[0][1]); atomicAdd(acc+2, sm[1][0]+sm[1][1]); }
}

__global__ __launch_bounds__(128) void k_rkd_dist(const float* __restrict__ ds,
    const float* __restrict__ dt, float* __restrict__ acc){
  int r=blockIdx.x, c=threadIdx.x;
  float mean_s = acc[1]*(1.f/8128.f) + 1e-8f;
  float mean_t = acc[2]*(1.f/8128.f) + 1e-8f;
  float h=0.f;
  if(c>r){
    float diff = ds[r*128+c]/mean_s - dt[r*128+c]/mean_t;
    float a = fabsf(diff);
    h = (a<1.f)? 0.5f*a*a : a-0.5f;
  }
  h = wred_sum(h);
  __shared__ float sm[2];
  if((threadIdx.x&63)==0) sm[threadIdx.x>>6]=h;
  __syncthreads();
  if(threadIdx.x==0) atomicAdd(acc+3, sm[0]+sm[1]);
}

// one block per vertex j; e-rows in LDS (127 rows, pitch 129 -> 65,532B dyn LDS)
__global__ __launch_bounds__(256) void k_rkd_angle(const float* __restrict__ sb,
    const float* __restrict__ tb, float* __restrict__ psibuf, float* __restrict__ acc){
  extern __shared__ float eLDS[];
  const int j = blockIdx.x;
  const int tid = threadIdx.x;
  float hsum = 0.f;
  for(int pass=0; pass<2; pass++){
    const float* xb = pass ? tb : sb;
    __syncthreads();
    if(tid < 128 && tid != j){
      const int i = tid;
      const int rr = i - (i > j ? 1 : 0);
      const float* xi = xb + i*128;
      const float* xj = xb + j*128;
      float ssq = 0.f;
      for(int d=0; d<128; d++){ float df = xj[d]-xi[d]; ssq += df*df; }
      float inv = 1.f/(sqrtf(ssq)+1e-8f);
      for(int d=0; d<128; d++) eLDS[rr*129+d] = (xj[d]-xi[d])*inv;
    }
    __syncthreads();
    for(int it=0; it<64; it++){
      int p = it*256 + tid;
      int i = p >> 7, k = p & 127;
      bool ok = (i!=j) && (k!=j) && (i!=k);
      float dot = 0.f;
      if(ok){
        const float* ei = eLDS + (size_t)(i-(i>j?1:0))*129;
        const float* ek = eLDS + (size_t)(k-(k>j?1:0))*129;
        for(int d=0; d<128; d++) dot += ei[d]*ek[d];
      }
      if(pass==0){ psibuf[(size_t)j*16384 + p] = dot; }
      else if(ok){
        float diff = psibuf[(size_t)j*16384 + p] - dot;
        float a = fabsf(diff);
        hsum += (a < 1.f) ? 0.5f*a*a : a - 0.5f;
      }
    }
  }
  hsum = wred_sum(hsum);
  if((tid & 63) == 0) atomicAdd(acc + 4, hsum);
}

// ---------------- Part B kernels ----------------
__global__ __launch_bounds__(256) void k_row_norm(const float* __restrict__ z,
    float* __restrict__ nrm, int K){
  int r = blockIdx.x;
  const float* row = z + (size_t)r*K;
  float ss=0.f;
  for(int d=threadIdx.x; d<K; d+=256){ float x=row[d]; ss+=x*x; }
  ss = wred_sum(ss);
  __shared__ float sm[4];
  if((threadIdx.x&63)==0) sm[threadIdx.x>>6]=ss;
  __syncthreads();
  if(threadIdx.x==0) nrm[r] = sqrtf(sm[0]+sm[1]+sm[2]+sm[3]);
}

// grid NB blocks, 256 threads (one per n): softmax of norms over N; also log(mu+1e-8)
__global__ __launch_bounds__(256) void k_saliency(const float* __restrict__ nrm,
    float* __restrict__ mu, float* __restrict__ logmu){
  int b = blockIdx.x, n = threadIdx.x;
  float x = nrm[b*NN+n];
  float mx = wred_max(x);
  __shared__ float sm[4], sm2[4];
  if((n&63)==0) sm[n>>6]=mx;
  __syncthreads();
  mx = fmaxf(fmaxf(sm[0],sm[1]),fmaxf(sm[2],sm[3]));
  float e = expf(x-mx);
  float s = wred_sum(e);
  if((n&63)==0) sm2[n>>6]=s;
  __syncthreads();
  s = sm2[0]+sm2[1]+sm2[2]+sm2[3];
  float m = e/s;
  mu[b*NN+n]=m;
  logmu[b*NN+n]=logf(m+1e-8f);
}

// C = A@W + bias ; A (Mrows x K) row-major, W (K x Ncols) row-major. 64x64x16 tiles.
__global__ __launch_bounds__(256) void k_gemm_proj(const float* __restrict__ A,
    const float* __restrict__ W, const float* __restrict__ bias,
    float* __restrict__ C, int Mrows, int Ncols, int K){
  __shared__ float As[16][68];
  __shared__ float Bs[16][68];
  int tid = threadIdx.x;
  int tx = tid & 15, ty = tid >> 4;
  int m0 = blockIdx.y*64, n0 = blockIdx.x*64;
  float acc[4][4] = {};
  int lrow = tid>>2, lkk = (tid&3)*4;    // A-tile load
  int brow = tid>>4, bcol = (tid&15)*4;  // B-tile load
  for(int k0=0;k0<K;k0+=16){
    float4 a4 = *(const float4*)(A + (size_t)(m0+lrow)*K + k0 + lkk);
    float4 b4 = *(const float4*)(W + (size_t)(k0+brow)*Ncols + n0 + bcol);
    As[lkk+0][lrow]=a4.x; As[lkk+1][lrow]=a4.y; As[lkk+2][lrow]=a4.z; As[lkk+3][lrow]=a4.w;
    *(float4*)&Bs[brow][bcol] = b4;
    __syncthreads();
    #pragma unroll
    for(int kk=0;kk<16;kk++){
      float a_[4], b_[4];
      #pragma unroll
      for(int i2=0;i2<4;i2++) a_[i2]=As[kk][ty*4+i2];
      #pragma unroll
      for(int j2=0;j2<4;j2++) b_[j2]=Bs[kk][tx*4+j2];
      #pragma unroll
      for(int i2=0;i2<4;i2++)
        #pragma unroll
        for(int j2=0;j2<4;j2++) acc[i2][j2] += a_[i2]*b_[j2];
    }
    __syncthreads();
  }
  #pragma unroll
  for(int i2=0;i2<4;i2++){
    int row = m0+ty*4+i2;
    #pragma unroll
    for(int j2=0;j2<4;j2++){
      int col = n0+tx*4+j2;
      C[(size_t)row*Ncols+col] = acc[i2][j2] + bias[col];
    }
  }
}

// batched: out[b,i,j] = 1 - (X_i . Y_j)/(max(nx_i,eps)*max(ny_j,eps)); X,Y (NB,NN,K)
__global__ __launch_bounds__(256) void k_cost(const float* __restrict__ X,
    const float* __restrict__ Y, const float* __restrict__ nx,
    const float* __restrict__ ny, float* __restrict__ out, int K){
  __shared__ float As[16][68];
  __shared__ float Bs[16][68];
  int b = blockIdx.z;
  const float* A  = X + (size_t)b*NN*K;
  const float* Bm = Y + (size_t)b*NN*K;
  float* O = out + (size_t)b*NN*NN;
  const float* nxb = nx + b*NN; const float* nyb = ny + b*NN;
  int tid = threadIdx.x;
  int tx = tid & 15, ty = tid >> 4;
  int m0 = blockIdx.y*64, n0 = blockIdx.x*64;
  float acc[4][4] = {};
  int lrow = tid>>2, lkk = (tid&3)*4;
  for(int k0=0;k0<K;k0+=16){
    float4 a4 = *(const float4*)(A  + (size_t)(m0+lrow)*K + k0 + lkk);
    float4 b4 = *(const float4*)(Bm + (size_t)(n0+lrow)*K + k0 + lkk);
    As[lkk+0][lrow]=a4.x; As[lkk+1][lrow]=a4.y; As[lkk+2][lrow]=a4.z; As[lkk+3][lrow]=a4.w;
    Bs[lkk+0][lrow]=b4.x; Bs[lkk+1][lrow]=b4.y; Bs[lkk+2][lrow]=b4.z; Bs[lkk+3][lrow]=b4.w;
    __syncthreads();
    #pragma unroll
    for(int kk=0;kk<16;kk++){
      float a_[4], b_[4];
      #pragma unroll
      for(int i2=0;i2<4;i2++) a_[i2]=As[kk][ty*4+i2];
      #pragma unroll
      for(int j2=0;j2<4;j2++) b_[j2]=Bs[kk][tx*4+j2];
      #pragma unroll
      for(int i2=0;i2<4;i2++)
        #pragma unroll
        for(int j2=0;j2<4;j2++) acc[i2][j2] += a_[i2]*b_[j2];
    }
    __syncthreads();
  }
  #pragma unroll
  for(int i2=0;i2<4;i2++){
    int row = m0+ty*4+i2;
    float ir = 1.f/fmaxf(nxb[row],1e-12f);
    #pragma unroll
    for(int j2=0;j2<4;j2++){
      int col = n0+tx*4+j2;
      float ic = 1.f/fmaxf(nyb[col],1e-12f);
      O[(size_t)row*NN+col] = 1.f - acc[i2][j2]*ir*ic;
    }
  }
}

// per-batch transpose 256x256
__global__ void k_transpose(const float* __restrict__ Min, float* __restrict__ Mout){
  int b = blockIdx.z;
  __shared__ float t[32][33];
  int i0 = blockIdx.y*32, j0 = blockIdx.x*32;
  int tx = threadIdx.x, ty = threadIdx.y;
  const float* Mb = Min + (size_t)b*NN*NN;
  float* Ob = Mout + (size_t)b*NN*NN;
  for(int r=0;r<32;r+=8) t[ty+r][tx] = Mb[(size_t)(i0+ty+r)*NN + j0+tx];
  __syncthreads();
  for(int r=0;r<32;r+=8) Ob[(size_t)(j0+ty+r)*NN + i0+tx] = t[tx][ty+r];
}

// out[r] = logvec[r] - LSE_m( -10*P[r,m] + vadd[b*NN+m] );  wave per row, 4 rows/block
__global__ __launch_bounds__(256) void k_sinkhorn(const float* __restrict__ P,
    const float* __restrict__ vadd, const float* __restrict__ logvec,
    float* __restrict__ outv){
  int w = threadIdx.x>>6, l = threadIdx.x&63;
  int r = blockIdx.x*4 + w;
  const float* Pr = P + (size_t)r*NN;
  const float* va = vadd + (r & ~(NN-1));
  float x[4]; float mx=-1e30f;
  #pragma unroll
  for(int q=0;q<4;q++){
    int m = l + q*64;
    x[q] = -10.f*Pr[m] + va[m];
    mx = fmaxf(mx, x[q]);
  }
  mx = wred_max(mx);
  float s=0.f;
  #pragma unroll
  for(int q=0;q<4;q++) s += expf(x[q]-mx);
  s = wred_sum(s);
  if(l==0) outv[r] = logvec[r] - (mx + logf(s));
}

// Gamma=exp(u-10M+v); rowsum; feat += sum(M*Gamma); write Gn = Gamma/(rowsum+1e-8)
__global__ __launch_bounds__(256) void k_gamma(const float* __restrict__ M_,
    const float* __restrict__ u, const float* __restrict__ v,
    float* __restrict__ Gn, float* __restrict__ acc){
  int w=threadIdx.x>>6, l=threadIdx.x&63;
  int r = blockIdx.x*4+w;
  const float* Mr = M_ + (size_t)r*NN;
  const float* vb = v + (r & ~(NN-1));
  float uu = u[r];
  float g[4]; float s=0.f, f=0.f;
  #pragma unroll
  for(int q=0;q<4;q++){
    int m = l + q*64;
    float mm = Mr[m];
    g[q] = expf(uu - 10.f*mm + vb[m]);
    s += g[q]; f += mm*g[q];
  }
  s = wred_sum(s); f = wred_sum(f);
  float inv = 1.f/(s+1e-8f);
  #pragma unroll
  for(int q=0;q<4;q++){
    int m = l + q*64;
    Gn[(size_t)r*NN+m] = g[q]*inv;
  }
  if(l==0) atomicAdd(acc+5, f);
}

// batched plain C = A@B, all 256x256 per batch
__global__ __launch_bounds__(256) void k_gemm_bat(const float* __restrict__ Ain,
    const float* __restrict__ Bin, float* __restrict__ Cout){
  __shared__ float As[16][68];
  __shared__ float Bs[16][68];
  int b = blockIdx.z;
  const float* A  = Ain + (size_t)b*NN*NN;
  const float* Bm = Bin + (size_t)b*NN*NN;
  float* C = Cout + (size_t)b*NN*NN;
  int tid = threadIdx.x;
  int tx = tid & 15, ty = tid >> 4;
  int m0 = blockIdx.y*64, n0 = blockIdx.x*64;
  float acc[4][4] = {};
  int lrow = tid>>2, lkk = (tid&3)*4;
  int brow = tid>>4, bcol = (tid&15)*4;
  for(int k0=0;k0<NN;k0+=16){
    float4 a4 = *(const float4*)(A + (size_t)(m0+lrow)*NN + k0 + lkk);
    float4 b4 = *(const float4*)(Bm + (size_t)(k0+brow)*NN + n0 + bcol);
    As[lkk+0][lrow]=a4.x; As[lkk+1][lrow]=a4.y; As[lkk+2][lrow]=a4.z; As[lkk+3][lrow]=a4.w;
    *(float4*)&Bs[brow][bcol] = b4;
    __syncthreads();
    #pragma unroll
    for(int kk=0;kk<16;kk++){
      float a_[4], b_[4];
      #pragma unroll
      for(int i2=0;i2<4;i2++) a_[i2]=As[kk][ty*4+i2];
      #pragma unroll
      for(int j2=0;j2<4;j2++) b_[j2]=Bs[kk][tx*4+j2];
      #pragma unroll
      for(int i2=0;i2<4;i2++)
        #pragma unroll
        for(int j2=0;j2<4;j2++) acc[i2][j2] += a_[i2]*b_[j2];
    }
    __syncthreads();
  }
  #pragma unroll
  for(int i2=0;i2<4;i2++){
    int row = m0+ty*4+i2;
    #pragma unroll
    for(int j2=0;j2<4;j2++) C[(size_t)row*NN + n0+tx*4+j2] = acc[i2][j2];
  }
}

// D = T@Gn^T per batch; accumulate sum((C_s - D)^2 * mu_n * mu_l)
__global__ __launch_bounds__(256) void k_struct(const float* __restrict__ Tm,
    const float* __restrict__ Gn, const float* __restrict__ Cs,
    const float* __restrict__ mu, float* __restrict__ acc){
  __shared__ float As[16][68];
  __shared__ float Bs[16][68];
  int b = blockIdx.z;
  const float* A  = Tm + (size_t)b*NN*NN;
  const float* Bm = Gn + (size_t)b*NN*NN;
  const float* Cb = Cs + (size_t)b*NN*NN;
  const float* mb = mu + b*NN;
  int tid = threadIdx.x;
  int tx = tid & 15, ty = tid >> 4;
  int m0 = blockIdx.y*64, n0 = blockIdx.x*64;
  float accu[4][4] = {};
  int lrow = tid>>2, lkk = (tid&3)*4;
  for(int k0=0;k0<NN;k0+=16){
    float4 a4 = *(const float4*)(A  + (size_t)(m0+lrow)*NN + k0 + lkk);
    float4 b4 = *(const float4*)(Bm + (size_t)(n0+lrow)*NN + k0 + lkk);
    As[lkk+0][lrow]=a4.x; As[lkk+1][lrow]=a4.y; As[lkk+2][lrow]=a4.z; As[lkk+3][lrow]=a4.w;
    Bs[lkk+0][lrow]=b4.x; Bs[lkk+1][lrow]=b4.y; Bs[lkk+2][lrow]=b4.z; Bs[lkk+3][lrow]=b4.w;
    __syncthreads();
    #pragma unroll
    for(int kk=0;kk<16;kk++){
      float a_[4], b_[4];
      #pragma unroll
      for(int i2=0;i2<4;i2++) a_[i2]=As[kk][ty*4+i2];
      #pragma unroll
      for(int j2=0;j2<4;j2++) b_[j2]=Bs[kk][tx*4+j2];
      #pragma unroll
      for(int i2=0;i2<4;i2++)
        #pragma unroll
        for(int j2=0;j2<4;j2++) accu[i2][j2] += a_[i2]*b_[j2];
    }
    __syncthreads();
  }
  float loc = 0.f;
  #pragma unroll
  for(int i2=0;i2<4;i2++){
    int row = m0+ty*4+i2;
    float mr = mb[row];
    #pragma unroll
    for(int j2=0;j2<4;j2++){
      int col = n0+tx*4+j2;
      float d = Cb[(size_t)row*NN+col] - accu[i2][j2];
      loc += d*d*mr*mb[col];
    }
  }
  loc = wred_sum(loc);
  __shared__ float sm[4];
  if((tid&63)==0) sm[tid>>6]=loc;
  __syncthreads();
  if(tid==0) atomicAdd(acc+6, sm[0]+sm[1]+sm[2]+sm[3]);
}

__global__ void k_final(const float* __restrict__ acc, float* __restrict__ out){
  // rkd: 10*(1*dist + 2*angle)*2 ; holo: 0.5*(0.5*feat + 0.5*struct)/B summed q,p
  out[0] = acc[0]
         + 20.f*acc[3]*(1.f/8128.f)
         + 40.f*acc[4]*(1.f/2048256.f)
         + 0.25f*(acc[5]+acc[6])*(1.f/64.f);
}

// ---------------- host ----------------
extern "C" void kernel_launch(void* const* d_in, const int* in_sizes, int n_in,
                              void* d_out, int out_size, void* d_ws, size_t ws_size,
                              hipStream_t stream) {
  const float* s_q_reps   = (const float*)d_in[0];
  const float* s_p_reps   = (const float*)d_in[1];
  const float* t_q_reps   = (const float*)d_in[2];
  const float* t_p_reps   = (const float*)d_in[3];
  const float* s_q_states = (const float*)d_in[4];
  const float* s_p_states = (const float*)d_in[5];
  const float* t_q_states = (const float*)d_in[6];
  const float* t_p_states = (const float*)d_in[7];
  const float* proj_w     = (const float*)d_in[8];
  const float* proj_b     = (const float*)d_in[9];
  float* ws = (float*)d_ws;
  float* acc = ws + OFF_ACC;

  hipMemsetAsync(acc, 0, 16*sizeof(float), stream);

  // ---- Part A ----
  k_l2norm_rows<<<64,256,0,stream>>>(s_q_reps, ws+OFF_SQ128, 768, 128);
  k_l2norm_rows<<<64,256,0,stream>>>(s_p_reps, ws+OFF_SP128, 768, 128);
  k_l2norm_rows<<<64,256,0,stream>>>(t_q_reps, ws+OFF_TQ128, 768, 128);
  k_l2norm_rows<<<64,256,0,stream>>>(t_p_reps, ws+OFF_TP128, 768, 128);
  k_l2norm_rows<<<64,256,0,stream>>>(s_q_reps, ws+OFF_SQ768, 768, 768);
  k_l2norm_rows<<<64,256,0,stream>>>(s_p_reps, ws+OFF_SP768, 768, 768);
  k_contrastive<<<64,64,0,stream>>>(ws+OFF_SQ128, ws+OFF_SP128, 128, 1.0f, acc);
  k_contrastive<<<64,64,0,stream>>>(ws+OFF_SQ768, ws+OFF_SP768, 768, 2.0f, acc);
  k_gram_ds<<<128,128,0,stream>>>(ws+OFF_SQ128, ws+OFF_TQ128, ws+OFF_DS, ws+OFF_DT, acc);
  k_rkd_dist<<<128,128,0,stream>>>(ws+OFF_DS, ws+OFF_DT, acc);
  k_rkd_angle<<<128,256,65532,stream>>>(ws+OFF_SQ128, ws+OFF_TQ128, ws+OFF_PSI, acc);

  // ---- Part B: fused GW for (q) then (p) ----
  for(int pass=0; pass<2; pass++){
    const float* zs = pass ? s_p_states : s_q_states;
    const float* zt = pass ? t_p_states : t_q_states;
    k_row_norm<<<ROWS,256,0,stream>>>(zs, ws+OFF_NS, HSS);
    k_row_norm<<<ROWS,256,0,stream>>>(zt, ws+OFF_NT, HTT);
    k_saliency<<<NB,256,0,stream>>>(ws+OFF_NS, ws+OFF_MU, ws+OFF_LOGMU);
    k_saliency<<<NB,256,0,stream>>>(ws+OFF_NT, ws+OFF_NU, ws+OFF_LOGNU);
    k_gemm_proj<<<dim3(HTT/64, ROWS/64),256,0,stream>>>(zs, proj_w, proj_b,
                                                        ws+OFF_ZSP, ROWS, HTT, HSS);
    k_row_norm<<<ROWS,256,0,stream>>>(ws+OFF_ZSP, ws+OFF_NSP, HTT);
    k_cost<<<dim3(4,4,NB),256,0,stream>>>(zs, zs, ws+OFF_NS, ws+OFF_NS, ws+OFF_CS, HSS);
    k_cost<<<dim3(4,4,NB),256,0,stream>>>(zt, zt, ws+OFF_NT, ws+OFF_NT, ws+OFF_CT, HTT);
    k_cost<<<dim3(4,4,NB),256,0,stream>>>(ws+OFF_ZSP, zt, ws+OFF_NSP, ws+OFF_NT, ws+OFF_M, HTT);
    k_transpose<<<dim3(8,8,NB),dim3(32,8),0,stream>>>(ws+OFF_M, ws+OFF_GN); // Mt
    hipMemsetAsync(ws+OFF_U, 0, ROWS*sizeof(float), stream);
    hipMemsetAsync(ws+OFF_V, 0, ROWS*sizeof(float), stream);
    for(int it=0; it<20; it++){
      k_sinkhorn<<<ROWS/4,256,0,stream>>>(ws+OFF_M,  ws+OFF_V, ws+OFF_LOGMU, ws+OFF_U);
      k_sinkhorn<<<ROWS/4,256,0,stream>>>(ws+OFF_GN, ws+OFF_U, ws+OFF_LOGNU, ws+OFF_V);
    }
    k_gamma<<<ROWS/4,256,0,stream>>>(ws+OFF_M, ws+OFF_U, ws+OFF_V, ws+OFF_GN, acc);
    k_gemm_bat<<<dim3(4,4,NB),256,0,stream>>>(ws+OFF_GN, ws+OFF_CT, ws+OFF_T);
    k_struct<<<dim3(4,4,NB),256,0,stream>>>(ws+OFF_T, ws+OFF_GN, ws+OFF_CS, ws+OFF_MU, acc);
  }
  k_final<<<1,1,0,stream>>>(acc, (float*)d_out);
}

// Round 2
// 1882.619 us; speedup vs baseline: 1.5615x; 1.5615x over previous
//
#include <hip/hip_runtime.h>
#include <math.h>

// Problem dims
#define NB   64      // batch B
#define NN   256     // tokens N
#define HSS  768     // H_S
#define HTT  1024    // H_T
#define ROWS (NB*NN) // 16384

typedef unsigned short u16;
typedef __attribute__((ext_vector_type(8))) short bf16x8;
typedef __attribute__((ext_vector_type(4))) float f32x4;

// ---------------- workspace layout (float offsets) ----------------
static const size_t OFF_ACC   = 0;                         // 16 floats accum
static const size_t OFF_SQ128 = 16;                        // 64*128
static const size_t OFF_SP128 = OFF_SQ128 + 64*128;
static const size_t OFF_TQ128 = OFF_SP128 + 64*128;
static const size_t OFF_TP128 = OFF_TQ128 + 64*128;
static const size_t OFF_SQ768 = OFF_TP128 + 64*128;
static const size_t OFF_SP768 = OFF_SQ768 + 64*768;
static const size_t OFF_DS    = OFF_SP768 + 64*768;        // 128*128
static const size_t OFF_DT    = OFF_DS + 128*128;
static const size_t OFF_M     = OFF_DT + 128*128;          // B*N*N f32
static const size_t OFF_MT    = OFF_M  + (size_t)NB*NN*NN; // f32
static const size_t OFF_CS    = OFF_MT + (size_t)NB*NN*NN; // f32
static const size_t OFF_PSI   = OFF_CS;                    // ALIAS: Part A only, before CS written
// bf16 buffers (sizes counted in float units = bf16count/2)
static const size_t OFF_ZS_BF  = OFF_CS    + (size_t)NB*NN*NN;      // 16384x768 bf16
static const size_t OFF_ZT_BF  = OFF_ZS_BF + (size_t)ROWS*HSS/2;    // 16384x1024 bf16
static const size_t OFF_WT_BF  = OFF_ZT_BF + (size_t)ROWS*HTT/2;    // 1024x768 bf16
static const size_t OFF_ZSP_BF = OFF_WT_BF + (size_t)HTT*HSS/2;     // 16384x1024 bf16
static const size_t OFF_GN_BF  = OFF_ZSP_BF+ (size_t)ROWS*HTT/2;    // B*N*N bf16
static const size_t OFF_CT_BF  = OFF_GN_BF + (size_t)NB*NN*NN/2;
static const size_t OFF_T_BF   = OFF_CT_BF + (size_t)NB*NN*NN/2;
static const size_t OFF_NS    = OFF_T_BF + (size_t)NB*NN*NN/2;
static const size_t OFF_NT    = OFF_NS + ROWS;
static const size_t OFF_NSP   = OFF_NT + ROWS;
static const size_t OFF_MU    = OFF_NSP + ROWS;
static const size_t OFF_NU    = OFF_MU + ROWS;
static const size_t OFF_LOGMU = OFF_NU + ROWS;
static const size_t OFF_LOGNU = OFF_LOGMU + ROWS;
static const size_t OFF_U     = OFF_LOGNU + ROWS;
static const size_t OFF_V     = OFF_U + ROWS;

// acc indices: 0=contrastive 1=ds_sum 2=dt_sum 3=dist_huber 4=angle_huber 5=feat 6=struct

// ---------------- helpers ----------------
__device__ __forceinline__ float wred_sum(float v){
  #pragma unroll
  for(int o=32;o>0;o>>=1) v += __shfl_xor(v,o,64);
  return v;
}
__device__ __forceinline__ float wred_max(float v){
  #pragma unroll
  for(int o=32;o>0;o>>=1) v = fmaxf(v, __shfl_xor(v,o,64));
  return v;
}
__device__ __forceinline__ u16 f2bf(float f){
  unsigned u = __float_as_uint(f);
  unsigned r = (u + 0x7fffu + ((u>>16)&1u)) >> 16;
  return (u16)r;
}
__device__ __forceinline__ float bf2f(u16 h){
  return __uint_as_float(((unsigned)h)<<16);
}

// ---------------- Part A kernels (unchanged) ----------------
__global__ __launch_bounds__(256) void k_l2norm_rows(const float* __restrict__ in,
    float* __restrict__ out, int k_in, int k_use){
  int r = blockIdx.x;
  const float* row = in + (size_t)r*k_in;
  float ss = 0.f;
  for(int d=threadIdx.x; d<k_use; d+=256){ float x=row[d]; ss += x*x; }
  ss = wred_sum(ss);
  __shared__ float sm[4];
  if((threadIdx.x&63)==0) sm[threadIdx.x>>6]=ss;
  __syncthreads();
  float tot = sm[0]+sm[1]+sm[2]+sm[3];
  float inv = 1.f / fmaxf(sqrtf(tot), 1e-12f);
  for(int d=threadIdx.x; d<k_use; d+=256) out[(size_t)r*k_use + d] = row[d]*inv;
}

__global__ __launch_bounds__(64) void k_contrastive(const float* __restrict__ q,
    const float* __restrict__ p, int dim, float weight, float* __restrict__ acc){
  int i = blockIdx.x, j = threadIdx.x;
  const float* qi = q + (size_t)i*dim;
  const float* pj = p + (size_t)j*dim;
  float dot = 0.f;
  for(int d=0; d<dim; d++) dot += qi[d]*pj[d];
  float s = dot / 0.07f;
  float mx = wred_max(s);
  float e = expf(s - mx);
  float Z = wred_sum(e);
  float logZ = mx + logf(Z);
  float diag = __shfl(s, i, 64);
  if(j==0) atomicAdd(acc+0, weight*(logZ - diag)*(1.f/64.f));
}

__global__ __launch_bounds__(128) void k_gram_ds(const float* __restrict__ sb,
    const float* __restrict__ tb, float* __restrict__ ds, float* __restrict__ dt,
    float* __restrict__ acc){
  int r = blockIdx.x, c = threadIdx.x;
  const float* sr = sb + r*128; const float* sc = sb + c*128;
  const float* tr = tb + r*128; const float* tc = tb + c*128;
  float dot_s=0,ssr=0,ssc=0,dot_t=0,tsr=0,tsc=0;
  for(int d=0; d<128; d++){
    float a=sr[d], b=sc[d]; dot_s += a*b; ssr += a*a; ssc += b*b;
    float at=tr[d], bt=tc[d]; dot_t += at*bt; tsr += at*at; tsc += bt*bt;
  }
  float dv = ssr + ssc - 2.f*dot_s;
  float tv = tsr + tsc - 2.f*dot_t;
  ds[r*128+c] = dv; dt[r*128+c] = tv;
  float ms = (c>r)? dv : 0.f;
  float mt = (c>r)? tv : 0.f;
  ms = wred_sum(ms); mt = wred_sum(mt);
  __shared__ float sm[2][2];
  if((threadIdx.x&63)==0){ sm[0][threadIdx.x>>6]=ms; sm[1][threadIdx.x>>6]=mt; }
  __syncthreads();
  if(threadIdx.x==0){ atomicAdd(acc+1, sm[0][0]+sm[0][1]); atomicAdd(acc+2, sm[1][0]+sm[1][1]); }
}

__global__ __launch_bounds__(128) void k_rkd_dist(const float* __restrict__ ds,
    const float* __restrict__ dt, float* __restrict__ acc){
  int r=blockIdx.x, c=threadIdx.x;
  float mean_s = acc[1]*(1.f/8128.f) + 1e-8f;
  float mean_t = acc[2]*(1.f/8128.f) + 1e-8f;
  float h=0.f;
  if(c>r){
    float diff = ds[r*128+c]/mean_s - dt[r*128+c]/mean_t;
    float a = fabsf(diff);
    h = (a<1.f)? 0.5f*a*a : a-0.5f;
  }
  h = wred_sum(h);
  __shared__ float sm[2];
  if((threadIdx.x&63)==0) sm[threadIdx.x>>6]=h;
  __syncthreads();
  if(threadIdx.x==0) atomicAdd(acc+3, sm[0]+sm[1]);
}

__global__ __launch_bounds__(256) void k_rkd_angle(const float* __restrict__ sb,
    const float* __restrict__ tb, float* __restrict__ psibuf, float* __restrict__ acc){
  extern __shared__ float eLDS[];
  const int j = blockIdx.x;
  const int tid = threadIdx.x;
  float hsum = 0.f;
  for(int pass=0; pass<2; pass++){
    const float* xb = pass ? tb : sb;
    __syncthreads();
    if(tid < 128 && tid != j){
      const int i = tid;
      const int rr = i - (i > j ? 1 : 0);
      const float* xi = xb + i*128;
      const float* xj = xb + j*128;
      float ssq = 0.f;
      for(int d=0; d<128; d++){ float df = xj[d]-xi[d]; ssq += df*df; }
      float inv = 1.f/(sqrtf(ssq)+1e-8f);
      for(int d=0; d<128; d++) eLDS[rr*129+d] = (xj[d]-xi[d])*inv;
    }
    __syncthreads();
    for(int it=0; it<64; it++){
      int p = it*256 + tid;
      int i = p >> 7, k = p & 127;
      bool ok = (i!=j) && (k!=j) && (i!=k);
      float dot = 0.f;
      if(ok){
        const float* ei = eLDS + (size_t)(i-(i>j?1:0))*129;
        const float* ek = eLDS + (size_t)(k-(k>j?1:0))*129;
        for(int d=0; d<128; d++) dot += ei[d]*ek[d];
      }
      if(pass==0){ psibuf[(size_t)j*16384 + p] = dot; }
      else if(ok){
        float diff = psibuf[(size_t)j*16384 + p] - dot;
        float a = fabsf(diff);
        hsum += (a < 1.f) ? 0.5f*a*a : a - 0.5f;
      }
    }
  }
  hsum = wred_sum(hsum);
  if((tid & 63) == 0) atomicAdd(acc + 4, hsum);
}

// ---------------- Part B: conversion / norm kernels ----------------
__global__ __launch_bounds__(256) void k_cvt_bf16(const float* __restrict__ in,
    u16* __restrict__ out, int n4){
  int i = blockIdx.x*256 + threadIdx.x;
  if(i < n4){
    float4 v = ((const float4*)in)[i];
    ushort4 o;
    o.x = f2bf(v.x); o.y = f2bf(v.y); o.z = f2bf(v.z); o.w = f2bf(v.w);
    ((ushort4*)out)[i] = o;
  }
}

// W (HSS x HTT) f32 -> Wt (HTT x HSS) bf16
__global__ void k_wt(const float* __restrict__ W, u16* __restrict__ Wt){
  __shared__ float t[32][33];
  int k0 = blockIdx.y*32, n0 = blockIdx.x*32;
  int tx = threadIdx.x, ty = threadIdx.y;
  for(int r=0;r<32;r+=8) t[ty+r][tx] = W[(size_t)(k0+ty+r)*HTT + n0+tx];
  __syncthreads();
  for(int r=0;r<32;r+=8) Wt[(size_t)(n0+ty+r)*HSS + k0+tx] = f2bf(t[tx][ty+r]);
}

__global__ __launch_bounds__(256) void k_row_norm(const float* __restrict__ z,
    float* __restrict__ nrm, int K){
  int r = blockIdx.x;
  const float* row = z + (size_t)r*K;
  float ss=0.f;
  for(int d=threadIdx.x; d<K; d+=256){ float x=row[d]; ss+=x*x; }
  ss = wred_sum(ss);
  __shared__ float sm[4];
  if((threadIdx.x&63)==0) sm[threadIdx.x>>6]=ss;
  __syncthreads();
  if(threadIdx.x==0) nrm[r] = sqrtf(sm[0]+sm[1]+sm[2]+sm[3]);
}

__global__ __launch_bounds__(256) void k_row_norm_bf16(const u16* __restrict__ z,
    float* __restrict__ nrm, int K){
  int r = blockIdx.x;
  const u16* row = z + (size_t)r*K;
  float ss=0.f;
  for(int d=threadIdx.x; d<K; d+=256){ float x=bf2f(row[d]); ss+=x*x; }
  ss = wred_sum(ss);
  __shared__ float sm[4];
  if((threadIdx.x&63)==0) sm[threadIdx.x>>6]=ss;
  __syncthreads();
  if(threadIdx.x==0) nrm[r] = sqrtf(sm[0]+sm[1]+sm[2]+sm[3]);
}

__global__ __launch_bounds__(256) void k_saliency(const float* __restrict__ nrm,
    float* __restrict__ mu, float* __restrict__ logmu){
  int b = blockIdx.x, n = threadIdx.x;
  float x = nrm[b*NN+n];
  float mx = wred_max(x);
  __shared__ float sm[4], sm2[4];
  if((n&63)==0) sm[n>>6]=mx;
  __syncthreads();
  mx = fmaxf(fmaxf(sm[0],sm[1]),fmaxf(sm[2],sm[3]));
  float e = expf(x-mx);
  float s = wred_sum(e);
  if((n&63)==0) sm2[n>>6]=s;
  __syncthreads();
  s = sm2[0]+sm2[1]+sm2[2]+sm2[3];
  float m = e/s;
  mu[b*NN+n]=m;
  logmu[b*NN+n]=logf(m+1e-8f);
}

// ---------------- The MFMA GEMM (NT form: C = A(MxK) * B(NxK)^T) ----------------
// 128x128 block tile, BK=32, 4 waves (64x64 quadrant each, 4x4 of 16x16x32 mfma).
// LDS chunks XOR-swizzled (slot = chunk ^ ((row>>1)&3)) -> 2-way bank aliasing max (free).
enum { MODE_PROJ=0, MODE_COST=1, MODE_PLAIN=2, MODE_STRUCT=3 };

template<int MODE>
__global__ __launch_bounds__(256) void k_mfma(
    const u16* __restrict__ A, int lda, long bA,
    const u16* __restrict__ B, int ldb, long bB,
    int K,
    float* __restrict__ outF, u16* __restrict__ outB, int ldo, long bO,
    const float* __restrict__ nx, const float* __restrict__ ny,
    const float* __restrict__ bias,
    const float* __restrict__ Cs, const float* __restrict__ mu,
    float* __restrict__ accp)
{
  __shared__ u16 As[128*32];
  __shared__ u16 Bs[128*32];
  __shared__ float red[4];
  int b = blockIdx.z;
  const u16* Ab = A + (size_t)b*bA;
  const u16* Bb = B + (size_t)b*bB;
  int tid = threadIdx.x;
  int lane = tid & 63, w = tid >> 6;
  int m0 = blockIdx.y*128, n0 = blockIdx.x*128;
  int row_off = (w>>1)*64, col_off = (w&1)*64;
  int q = lane>>4, loc = lane&15;
  f32x4 acc[4][4] = {};
  int srow = tid >> 2;   // 0..63
  int skc  = tid & 3;    // chunk of 8 bf16 within BK=32

  for(int k0=0;k0<K;k0+=32){
    #pragma unroll
    for(int h=0;h<2;h++){
      int row = srow + h*64;
      int slot = skc ^ ((row>>1)&3);
      uint4 av = *(const uint4*)(Ab + (size_t)(m0+row)*lda + k0 + skc*8);
      uint4 bv = *(const uint4*)(Bb + (size_t)(n0+row)*ldb + k0 + skc*8);
      *(uint4*)(As + row*32 + slot*8) = av;
      *(uint4*)(Bs + row*32 + slot*8) = bv;
    }
    __syncthreads();
    bf16x8 af[4], bfr[4];
    #pragma unroll
    for(int mi=0;mi<4;mi++){
      int r = row_off + mi*16 + loc;
      int slot = q ^ ((r>>1)&3);
      af[mi] = *(const bf16x8*)(As + r*32 + slot*8);
    }
    #pragma unroll
    for(int ni=0;ni<4;ni++){
      int r = col_off + ni*16 + loc;
      int slot = q ^ ((r>>1)&3);
      bfr[ni] = *(const bf16x8*)(Bs + r*32 + slot*8);
    }
    #pragma unroll
    for(int mi=0;mi<4;mi++)
      #pragma unroll
      for(int ni=0;ni<4;ni++)
        acc[mi][ni] = __builtin_amdgcn_mfma_f32_16x16x32_bf16(af[mi], bfr[ni], acc[mi][ni], 0,0,0);
    __syncthreads();
  }

  // epilogue: D[row][col], row = quad*4+reg, col = lane&15  (measured m89/m91)
  float* outFb = outF ? outF + (size_t)b*bO : nullptr;
  u16*   outBb = outB ? outB + (size_t)b*bO : nullptr;
  const float* nxb = nx ? nx + (size_t)b*NN : nullptr;
  const float* nyb = ny ? ny + (size_t)b*NN : nullptr;
  const float* Cb  = (MODE==MODE_STRUCT) ? Cs + (size_t)b*bO : nullptr;
  const float* mb  = (MODE==MODE_STRUCT) ? mu + (size_t)b*NN : nullptr;
  float lsum = 0.f;
  #pragma unroll
  for(int mi=0;mi<4;mi++){
    #pragma unroll
    for(int j=0;j<4;j++){
      int row = m0 + row_off + mi*16 + q*4 + j;
      float ir = 0.f, mr = 0.f;
      if(MODE==MODE_COST)   ir = 1.f/fmaxf(nxb[row],1e-12f);
      if(MODE==MODE_STRUCT) mr = mb[row];
      #pragma unroll
      for(int ni=0;ni<4;ni++){
        int col = n0 + col_off + ni*16 + loc;
        float v = acc[mi][ni][j];
        if(MODE==MODE_PROJ){
          v += bias[col];
          outBb[(size_t)row*ldo + col] = f2bf(v);
        } else if(MODE==MODE_COST){
          float ic = 1.f/fmaxf(nyb[col],1e-12f);
          v = 1.f - v*ir*ic;
          if(outFb) outFb[(size_t)row*ldo + col] = v;
          if(outBb) outBb[(size_t)row*ldo + col] = f2bf(v);
        } else if(MODE==MODE_PLAIN){
          outBb[(size_t)row*ldo + col] = f2bf(v);
        } else {
          float d = Cb[(size_t)row*ldo + col] - v;
          lsum += d*d*mr*mb[col];
        }
      }
    }
  }
  if(MODE==MODE_STRUCT){
    lsum = wred_sum(lsum);
    if(lane==0) red[w] = lsum;
    __syncthreads();
    if(tid==0) atomicAdd(accp+6, red[0]+red[1]+red[2]+red[3]);
  }
}

// ---------------- Sinkhorn (unchanged f32) ----------------
__global__ void k_transpose(const float* __restrict__ Min, float* __restrict__ Mout){
  int b = blockIdx.z;
  __shared__ float t[32][33];
  int i0 = blockIdx.y*32, j0 = blockIdx.x*32;
  int tx = threadIdx.x, ty = threadIdx.y;
  const float* Mb = Min + (size_t)b*NN*NN;
  float* Ob = Mout + (size_t)b*NN*NN;
  for(int r=0;r<32;r+=8) t[ty+r][tx] = Mb[(size_t)(i0+ty+r)*NN + j0+tx];
  __syncthreads();
  for(int r=0;r<32;r+=8) Ob[(size_t)(j0+ty+r)*NN + i0+tx] = t[tx][ty+r];
}

__global__ __launch_bounds__(256) void k_sinkhorn(const float* __restrict__ P,
    const float* __restrict__ vadd, const float* __restrict__ logvec,
    float* __restrict__ outv){
  int w = threadIdx.x>>6, l = threadIdx.x&63;
  int r = blockIdx.x*4 + w;
  const float* Pr = P + (size_t)r*NN;
  const float* va = vadd + (r & ~(NN-1));
  float x[4]; float mx=-1e30f;
  #pragma unroll
  for(int qq=0;qq<4;qq++){
    int m = l + qq*64;
    x[qq] = -10.f*Pr[m] + va[m];
    mx = fmaxf(mx, x[qq]);
  }
  mx = wred_max(mx);
  float s=0.f;
  #pragma unroll
  for(int qq=0;qq<4;qq++) s += expf(x[qq]-mx);
  s = wred_sum(s);
  if(l==0) outv[r] = logvec[r] - (mx + logf(s));
}

__global__ __launch_bounds__(256) void k_gamma(const float* __restrict__ M_,
    const float* __restrict__ u, const float* __restrict__ v,
    u16* __restrict__ Gn, float* __restrict__ acc){
  int w=threadIdx.x>>6, l=threadIdx.x&63;
  int r = blockIdx.x*4+w;
  const float* Mr = M_ + (size_t)r*NN;
  const float* vb = v + (r & ~(NN-1));
  float uu = u[r];
  float g[4]; float s=0.f, f=0.f;
  #pragma unroll
  for(int qq=0;qq<4;qq++){
    int m = l + qq*64;
    float mm = Mr[m];
    g[qq] = expf(uu - 10.f*mm + vb[m]);
    s += g[qq]; f += mm*g[qq];
  }
  s = wred_sum(s); f = wred_sum(f);
  float inv = 1.f/(s+1e-8f);
  #pragma unroll
  for(int qq=0;qq<4;qq++){
    int m = l + qq*64;
    Gn[(size_t)r*NN+m] = f2bf(g[qq]*inv);
  }
  if(l==0) atomicAdd(acc+5, f);
}

__global__ void k_final(const float* __restrict__ acc, float* __restrict__ out){
  out[0] = acc[0]
         + 20.f*acc[3]*(1.f/8128.f)
         + 40.f*acc[4]*(1.f/2048256.f)
         + 0.25f*(acc[5]+acc[6])*(1.f/64.f);
}

// ---------------- host ----------------
extern "C" void kernel_launch(void* const* d_in, const int* in_sizes, int n_in,
                              void* d_out, int out_size, void* d_ws, size_t ws_size,
                              hipStream_t stream) {
  const float* s_q_reps   = (const float*)d_in[0];
  const float* s_p_reps   = (const float*)d_in[1];
  const float* t_q_reps   = (const float*)d_in[2];
  const float* t_p_reps   = (const float*)d_in[3];
  const float* s_q_states = (const float*)d_in[4];
  const float* s_p_states = (const float*)d_in[5];
  const float* t_q_states = (const float*)d_in[6];
  const float* t_p_states = (const float*)d_in[7];
  const float* proj_w     = (const float*)d_in[8];
  const float* proj_b     = (const float*)d_in[9];
  float* ws = (float*)d_ws;
  float* acc = ws + OFF_ACC;
  u16* ZS_BF  = (u16*)(ws + OFF_ZS_BF);
  u16* ZT_BF  = (u16*)(ws + OFF_ZT_BF);
  u16* WT_BF  = (u16*)(ws + OFF_WT_BF);
  u16* ZSP_BF = (u16*)(ws + OFF_ZSP_BF);
  u16* GN_BF  = (u16*)(ws + OFF_GN_BF);
  u16* CT_BF  = (u16*)(ws + OFF_CT_BF);
  u16* T_BF   = (u16*)(ws + OFF_T_BF);

  hipMemsetAsync(acc, 0, 16*sizeof(float), stream);

  // ---- Part A ----
  k_l2norm_rows<<<64,256,0,stream>>>(s_q_reps, ws+OFF_SQ128, 768, 128);
  k_l2norm_rows<<<64,256,0,stream>>>(s_p_reps, ws+OFF_SP128, 768, 128);
  k_l2norm_rows<<<64,256,0,stream>>>(t_q_reps, ws+OFF_TQ128, 768, 128);
  k_l2norm_rows<<<64,256,0,stream>>>(t_p_reps, ws+OFF_TP128, 768, 128);
  k_l2norm_rows<<<64,256,0,stream>>>(s_q_reps, ws+OFF_SQ768, 768, 768);
  k_l2norm_rows<<<64,256,0,stream>>>(s_p_reps, ws+OFF_SP768, 768, 768);
  k_contrastive<<<64,64,0,stream>>>(ws+OFF_SQ128, ws+OFF_SP128, 128, 1.0f, acc);
  k_contrastive<<<64,64,0,stream>>>(ws+OFF_SQ768, ws+OFF_SP768, 768, 2.0f, acc);
  k_gram_ds<<<128,128,0,stream>>>(ws+OFF_SQ128, ws+OFF_TQ128, ws+OFF_DS, ws+OFF_DT, acc);
  k_rkd_dist<<<128,128,0,stream>>>(ws+OFF_DS, ws+OFF_DT, acc);
  k_rkd_angle<<<128,256,65532,stream>>>(ws+OFF_SQ128, ws+OFF_TQ128, ws+OFF_PSI, acc);

  // W transpose+convert (once)
  k_wt<<<dim3(HTT/32, HSS/32),dim3(32,8),0,stream>>>(proj_w, WT_BF);

  // ---- Part B: fused GW for (q) then (p) ----
  for(int pass=0; pass<2; pass++){
    const float* zs = pass ? s_p_states : s_q_states;
    const float* zt = pass ? t_p_states : t_q_states;
    k_cvt_bf16<<<(ROWS*HSS/4+255)/256,256,0,stream>>>(zs, ZS_BF, ROWS*HSS/4);
    k_cvt_bf16<<<(ROWS*HTT/4+255)/256,256,0,stream>>>(zt, ZT_BF, ROWS*HTT/4);
    k_row_norm<<<ROWS,256,0,stream>>>(zs, ws+OFF_NS, HSS);
    k_row_norm<<<ROWS,256,0,stream>>>(zt, ws+OFF_NT, HTT);
    k_saliency<<<NB,256,0,stream>>>(ws+OFF_NS, ws+OFF_MU, ws+OFF_LOGMU);
    k_saliency<<<NB,256,0,stream>>>(ws+OFF_NT, ws+OFF_NU, ws+OFF_LOGNU);
    // proj: ZSP = ZS @ Wt^T + b   (16384x1024)
    k_mfma<MODE_PROJ><<<dim3(HTT/128, ROWS/128, 1),256,0,stream>>>(
        ZS_BF, HSS, 0, WT_BF, HSS, 0, HSS,
        nullptr, ZSP_BF, HTT, 0,
        nullptr, nullptr, proj_b, nullptr, nullptr, nullptr);
    k_row_norm_bf16<<<ROWS,256,0,stream>>>(ZSP_BF, ws+OFF_NSP, HTT);
    // C_s (f32)
    k_mfma<MODE_COST><<<dim3(2,2,NB),256,0,stream>>>(
        ZS_BF, HSS, (long)NN*HSS, ZS_BF, HSS, (long)NN*HSS, HSS,
        ws+OFF_CS, nullptr, NN, (long)NN*NN,
        ws+OFF_NS, ws+OFF_NS, nullptr, nullptr, nullptr, nullptr);
    // C_t (bf16 only; exactly symmetric)
    k_mfma<MODE_COST><<<dim3(2,2,NB),256,0,stream>>>(
        ZT_BF, HTT, (long)NN*HTT, ZT_BF, HTT, (long)NN*HTT, HTT,
        nullptr, CT_BF, NN, (long)NN*NN,
        ws+OFF_NT, ws+OFF_NT, nullptr, nullptr, nullptr, nullptr);
    // M (f32)
    k_mfma<MODE_COST><<<dim3(2,2,NB),256,0,stream>>>(
        ZSP_BF, HTT, (long)NN*HTT, ZT_BF, HTT, (long)NN*HTT, HTT,
        ws+OFF_M, nullptr, NN, (long)NN*NN,
        ws+OFF_NSP, ws+OFF_NT, nullptr, nullptr, nullptr, nullptr);
    // Sinkhorn
    k_transpose<<<dim3(8,8,NB),dim3(32,8),0,stream>>>(ws+OFF_M, ws+OFF_MT);
    hipMemsetAsync(ws+OFF_U, 0, ROWS*sizeof(float), stream);
    hipMemsetAsync(ws+OFF_V, 0, ROWS*sizeof(float), stream);
    for(int it=0; it<20; it++){
      k_sinkhorn<<<ROWS/4,256,0,stream>>>(ws+OFF_M,  ws+OFF_V, ws+OFF_LOGMU, ws+OFF_U);
      k_sinkhorn<<<ROWS/4,256,0,stream>>>(ws+OFF_MT, ws+OFF_U, ws+OFF_LOGNU, ws+OFF_V);
    }
    k_gamma<<<ROWS/4,256,0,stream>>>(ws+OFF_M, ws+OFF_U, ws+OFF_V, GN_BF, acc);
    // T = Gn @ Ct (Ct symmetric -> NT form), bf16
    k_mfma<MODE_PLAIN><<<dim3(2,2,NB),256,0,stream>>>(
        GN_BF, NN, (long)NN*NN, CT_BF, NN, (long)NN*NN, NN,
        nullptr, T_BF, NN, (long)NN*NN,
        nullptr, nullptr, nullptr, nullptr, nullptr, nullptr);
    // struct: sum((Cs - T@Gn^T)^2 * mu mu^T)
    k_mfma<MODE_STRUCT><<<dim3(2,2,NB),256,0,stream>>>(
        T_BF, NN, (long)NN*NN, GN_BF, NN, (long)NN*NN, NN,
        nullptr, nullptr, NN, (long)NN*NN,
        nullptr, nullptr, nullptr, ws+OFF_CS, ws+OFF_MU, acc);
  }
  k_final<<<1,1,0,stream>>>(acc, (float*)d_out);
}

// Round 3
// 1503.276 us; speedup vs baseline: 1.9555x; 1.2523x over previous
//
#include <hip/hip_runtime.h>
#include <math.h>

// Problem dims
#define NB   64      // batch B
#define NN   256     // tokens N
#define HSS  768     // H_S
#define HTT  1024    // H_T
#define ROWS (NB*NN) // 16384
#define C2LOG 14.426950408889634f  // 10 * log2(e)  (OT eps=0.1 -> -10*M in exponent)

typedef unsigned short u16;
typedef __attribute__((ext_vector_type(8))) short bf16x8;
typedef __attribute__((ext_vector_type(4))) float f32x4;

// ---------------- workspace layout (float offsets) ----------------
static const size_t OFF_ACC   = 0;                          // 16 floats
static const size_t OFF_SQ128 = 16;
static const size_t OFF_SP128 = OFF_SQ128 + 64*128;
static const size_t OFF_TQ128 = OFF_SP128 + 64*128;
static const size_t OFF_TP128 = OFF_TQ128 + 64*128;
static const size_t OFF_SQ768 = OFF_TP128 + 64*128;
static const size_t OFF_SP768 = OFF_SQ768 + 64*768;
static const size_t OFF_DS    = OFF_SP768 + 64*768;         // 128*128
static const size_t OFF_DT    = OFF_DS + 128*128;
// doubled (both GW passes) f32 C_s
static const size_t OFF_CS    = OFF_DT + 128*128;           // 2*B*N*N f32
static const size_t OFF_PSI   = OFF_CS;                     // ALIAS: Part A only (needs 2.1M < 8.4M)
// bf16 buffers (float units = u16count/2)
static const size_t OFF_MBF   = OFF_CS  + (size_t)2*NB*NN*NN;     // 2*B*N*N bf16
static const size_t OFF_MTBF  = OFF_MBF + (size_t)NB*NN*NN;       // 2*B*N*N bf16
static const size_t OFF_ZS_BF = OFF_MTBF+ (size_t)NB*NN*NN;       // 16384x768 bf16
static const size_t OFF_ZT_BF = OFF_ZS_BF + (size_t)ROWS*HSS/2;   // 16384x1024 bf16
static const size_t OFF_WT_BF = OFF_ZT_BF + (size_t)ROWS*HTT/2;   // 1024x768 bf16
static const size_t OFF_ZSP_BF= OFF_WT_BF + (size_t)HTT*HSS/2;    // 16384x1024 bf16
static const size_t OFF_GN_BF = OFF_ZSP_BF+ (size_t)ROWS*HTT/2;   // 2*B*N*N bf16
static const size_t OFF_CT_BF = OFF_GN_BF + (size_t)NB*NN*NN;     // 2*B*N*N bf16
static const size_t OFF_T_BF  = OFF_ZS_BF;                  // ALIAS: ZS dead after cost GEMMs
static const size_t OFF_NS    = OFF_CT_BF + (size_t)NB*NN*NN;
static const size_t OFF_NT    = OFF_NS + ROWS;
static const size_t OFF_NSP   = OFF_NT + ROWS;
static const size_t OFF_MU    = OFF_NSP + ROWS;             // 2*ROWS
static const size_t OFF_LOGMU = OFF_MU + 2*ROWS;            // 2*ROWS (log2 domain)
static const size_t OFF_LOGNU = OFF_LOGMU + 2*ROWS;         // 2*ROWS (log2 domain)

// acc: 0=contrastive 1=ds_sum 2=dt_sum 3=dist_huber 4=angle_huber 5=feat 6=struct

// ---------------- helpers ----------------
__device__ __forceinline__ float wred_sum(float v){
  #pragma unroll
  for(int o=32;o>0;o>>=1) v += __shfl_xor(v,o,64);
  return v;
}
__device__ __forceinline__ float wred_max(float v){
  #pragma unroll
  for(int o=32;o>0;o>>=1) v = fmaxf(v, __shfl_xor(v,o,64));
  return v;
}
__device__ __forceinline__ u16 f2bf(float f){
  unsigned u = __float_as_uint(f);
  unsigned r = (u + 0x7fffu + ((u>>16)&1u)) >> 16;
  return (u16)r;
}
__device__ __forceinline__ float bf2f(u16 h){
  return __uint_as_float(((unsigned)h)<<16);
}

// ---------------- Part A kernels ----------------
__global__ __launch_bounds__(256) void k_l2norm_rows(const float* __restrict__ in,
    float* __restrict__ out, int k_in, int k_use){
  int r = blockIdx.x;
  const float* row = in + (size_t)r*k_in;
  float ss = 0.f;
  for(int d=threadIdx.x; d<k_use; d+=256){ float x=row[d]; ss += x*x; }
  ss = wred_sum(ss);
  __shared__ float sm[4];
  if((threadIdx.x&63)==0) sm[threadIdx.x>>6]=ss;
  __syncthreads();
  float tot = sm[0]+sm[1]+sm[2]+sm[3];
  float inv = 1.f / fmaxf(sqrtf(tot), 1e-12f);
  for(int d=threadIdx.x; d<k_use; d+=256) out[(size_t)r*k_use + d] = row[d]*inv;
}

__global__ __launch_bounds__(64) void k_contrastive(const float* __restrict__ q,
    const float* __restrict__ p, int dim, float weight, float* __restrict__ acc){
  int i = blockIdx.x, j = threadIdx.x;
  const float* qi = q + (size_t)i*dim;
  const float* pj = p + (size_t)j*dim;
  float dot = 0.f;
  for(int d=0; d<dim; d++) dot += qi[d]*pj[d];
  float s = dot / 0.07f;
  float mx = wred_max(s);
  float e = expf(s - mx);
  float Z = wred_sum(e);
  float logZ = mx + logf(Z);
  float diag = __shfl(s, i, 64);
  if(j==0) atomicAdd(acc+0, weight*(logZ - diag)*(1.f/64.f));
}

__global__ __launch_bounds__(128) void k_gram_ds(const float* __restrict__ sb,
    const float* __restrict__ tb, float* __restrict__ ds, float* __restrict__ dt,
    float* __restrict__ acc){
  int r = blockIdx.x, c = threadIdx.x;
  const float* sr = sb + r*128; const float* sc = sb + c*128;
  const float* tr = tb + r*128; const float* tc = tb + c*128;
  float dot_s=0,ssr=0,ssc=0,dot_t=0,tsr=0,tsc=0;
  for(int d=0; d<128; d++){
    float a=sr[d], b=sc[d]; dot_s += a*b; ssr += a*a; ssc += b*b;
    float at=tr[d], bt=tc[d]; dot_t += at*bt; tsr += at*at; tsc += bt*bt;
  }
  float dv = ssr + ssc - 2.f*dot_s;
  float tv = tsr + tsc - 2.f*dot_t;
  ds[r*128+c] = dv; dt[r*128+c] = tv;
  float ms = (c>r)? dv : 0.f;
  float mt = (c>r)? tv : 0.f;
  ms = wred_sum(ms); mt = wred_sum(mt);
  __shared__ float sm[2][2];
  if((threadIdx.x&63)==0){ sm[0][threadIdx.x>>6]=ms; sm[1][threadIdx.x>>6]=mt; }
  __syncthreads();
  if(threadIdx.x==0){ atomicAdd(acc+1, sm[0][0]+sm[0][1]); atomicAdd(acc+2, sm[1][0]+sm[1][1]); }
}

__global__ __launch_bounds__(128) void k_rkd_dist(const float* __restrict__ ds,
    const float* __restrict__ dt, float* __restrict__ acc){
  int r=blockIdx.x, c=threadIdx.x;
  float mean_s = acc[1]*(1.f/8128.f) + 1e-8f;
  float mean_t = acc[2]*(1.f/8128.f) + 1e-8f;
  float h=0.f;
  if(c>r){
    float diff = ds[r*128+c]/mean_s - dt[r*128+c]/mean_t;
    float a = fabsf(diff);
    h = (a<1.f)? 0.5f*a*a : a-0.5f;
  }
  h = wred_sum(h);
  __shared__ float sm[2];
  if((threadIdx.x&63)==0) sm[threadIdx.x>>6]=h;
  __syncthreads();
  if(threadIdx.x==0) atomicAdd(acc+3, sm[0]+sm[1]);
}

__global__ __launch_bounds__(256) void k_rkd_angle(const float* __restrict__ sb,
    const float* __restrict__ tb, float* __restrict__ psibuf, float* __restrict__ acc){
  extern __shared__ float eLDS[];
  const int j = blockIdx.x;
  const int tid = threadIdx.x;
  float hsum = 0.f;
  for(int pass=0; pass<2; pass++){
    const float* xb = pass ? tb : sb;
    __syncthreads();
    if(tid < 128 && tid != j){
      const int i = tid;
      const int rr = i - (i > j ? 1 : 0);
      const float* xi = xb + i*128;
      const float* xj = xb + j*128;
      float ssq = 0.f;
      for(int d=0; d<128; d++){ float df = xj[d]-xi[d]; ssq += df*df; }
      float inv = 1.f/(sqrtf(ssq)+1e-8f);
      for(int d=0; d<128; d++) eLDS[rr*129+d] = (xj[d]-xi[d])*inv;
    }
    __syncthreads();
    for(int it=0; it<64; it++){
      int p = it*256 + tid;
      int i = p >> 7, k = p & 127;
      bool ok = (i!=j) && (k!=j) && (i!=k);
      float dot = 0.f;
      if(ok){
        const float* ei = eLDS + (size_t)(i-(i>j?1:0))*129;
        const float* ek = eLDS + (size_t)(k-(k>j?1:0))*129;
        for(int d=0; d<128; d++) dot += ei[d]*ek[d];
      }
      if(pass==0){ psibuf[(size_t)j*16384 + p] = dot; }
      else if(ok){
        float diff = psibuf[(size_t)j*16384 + p] - dot;
        float a = fabsf(diff);
        hsum += (a < 1.f) ? 0.5f*a*a : a - 0.5f;
      }
    }
  }
  hsum = wred_sum(hsum);
  if((tid & 63) == 0) atomicAdd(acc + 4, hsum);
}

// ---------------- Part B: convert+norm / saliency ----------------
// fused: write bf16 copy AND compute row L2 norm in one read
__global__ __launch_bounds__(256) void k_cvt_norm(const float* __restrict__ in,
    u16* __restrict__ out, float* __restrict__ nrm, int K){
  int r = blockIdx.x;
  const float* row = in + (size_t)r*K;
  u16* orow = out + (size_t)r*K;
  float ss=0.f;
  for(int d=threadIdx.x; d<K; d+=256){ float x=row[d]; ss+=x*x; orow[d]=f2bf(x); }
  ss = wred_sum(ss);
  __shared__ float sm[4];
  if((threadIdx.x&63)==0) sm[threadIdx.x>>6]=ss;
  __syncthreads();
  if(threadIdx.x==0) nrm[r] = sqrtf(sm[0]+sm[1]+sm[2]+sm[3]);
}

__global__ __launch_bounds__(256) void k_row_norm_bf16(const u16* __restrict__ z,
    float* __restrict__ nrm, int K){
  int r = blockIdx.x;
  const u16* row = z + (size_t)r*K;
  float ss=0.f;
  for(int d=threadIdx.x; d<K; d+=256){ float x=bf2f(row[d]); ss+=x*x; }
  ss = wred_sum(ss);
  __shared__ float sm[4];
  if((threadIdx.x&63)==0) sm[threadIdx.x>>6]=ss;
  __syncthreads();
  if(threadIdx.x==0) nrm[r] = sqrtf(sm[0]+sm[1]+sm[2]+sm[3]);
}

// W (HSS x HTT) f32 -> Wt (HTT x HSS) bf16
__global__ void k_wt(const float* __restrict__ W, u16* __restrict__ Wt){
  __shared__ float t[32][33];
  int k0 = blockIdx.y*32, n0 = blockIdx.x*32;
  int tx = threadIdx.x, ty = threadIdx.y;
  for(int r=0;r<32;r+=8) t[ty+r][tx] = W[(size_t)(k0+ty+r)*HTT + n0+tx];
  __syncthreads();
  for(int r=0;r<32;r+=8) Wt[(size_t)(n0+ty+r)*HSS + k0+tx] = f2bf(t[tx][ty+r]);
}

// softmax over N; logmu emitted in LOG2 domain (for exp2-based Sinkhorn)
__global__ __launch_bounds__(256) void k_saliency(const float* __restrict__ nrm,
    float* __restrict__ mu, float* __restrict__ logmu2){
  int b = blockIdx.x, n = threadIdx.x;
  float x = nrm[b*NN+n];
  float mx = wred_max(x);
  __shared__ float sm[4], sm2[4];
  if((n&63)==0) sm[n>>6]=mx;
  __syncthreads();
  mx = fmaxf(fmaxf(sm[0],sm[1]),fmaxf(sm[2],sm[3]));
  float e = expf(x-mx);
  float s = wred_sum(e);
  if((n&63)==0) sm2[n>>6]=s;
  __syncthreads();
  s = sm2[0]+sm2[1]+sm2[2]+sm2[3];
  float m = e/s;
  if(mu) mu[b*NN+n]=m;
  logmu2[b*NN+n]=log2f(m+1e-8f);
}

// ---------------- MFMA GEMM (NT form) ----------------
enum { MODE_PROJ=0, MODE_COST=1, MODE_PLAIN=2, MODE_STRUCT=3 };

template<int MODE>
__global__ __launch_bounds__(256) void k_mfma(
    const u16* __restrict__ A, int lda, long bA,
    const u16* __restrict__ B, int ldb, long bB,
    int K,
    float* __restrict__ outF, u16* __restrict__ outB, int ldo, long bO,
    const float* __restrict__ nx, const float* __restrict__ ny,
    const float* __restrict__ bias,
    const float* __restrict__ Cs, const float* __restrict__ mu,
    float* __restrict__ accp)
{
  __shared__ u16 As[128*32];
  __shared__ u16 Bs[128*32];
  __shared__ float red[4];
  int b = blockIdx.z;
  const u16* Ab = A + (size_t)b*bA;
  const u16* Bb = B + (size_t)b*bB;
  int tid = threadIdx.x;
  int lane = tid & 63, w = tid >> 6;
  int m0 = blockIdx.y*128, n0 = blockIdx.x*128;
  int row_off = (w>>1)*64, col_off = (w&1)*64;
  int q = lane>>4, loc = lane&15;
  f32x4 acc[4][4] = {};
  int srow = tid >> 2;
  int skc  = tid & 3;

  for(int k0=0;k0<K;k0+=32){
    #pragma unroll
    for(int h=0;h<2;h++){
      int row = srow + h*64;
      int slot = skc ^ ((row>>1)&3);
      uint4 av = *(const uint4*)(Ab + (size_t)(m0+row)*lda + k0 + skc*8);
      uint4 bv = *(const uint4*)(Bb + (size_t)(n0+row)*ldb + k0 + skc*8);
      *(uint4*)(As + row*32 + slot*8) = av;
      *(uint4*)(Bs + row*32 + slot*8) = bv;
    }
    __syncthreads();
    bf16x8 af[4], bfr[4];
    #pragma unroll
    for(int mi=0;mi<4;mi++){
      int r = row_off + mi*16 + loc;
      int slot = q ^ ((r>>1)&3);
      af[mi] = *(const bf16x8*)(As + r*32 + slot*8);
    }
    #pragma unroll
    for(int ni=0;ni<4;ni++){
      int r = col_off + ni*16 + loc;
      int slot = q ^ ((r>>1)&3);
      bfr[ni] = *(const bf16x8*)(Bs + r*32 + slot*8);
    }
    #pragma unroll
    for(int mi=0;mi<4;mi++)
      #pragma unroll
      for(int ni=0;ni<4;ni++)
        acc[mi][ni] = __builtin_amdgcn_mfma_f32_16x16x32_bf16(af[mi], bfr[ni], acc[mi][ni], 0,0,0);
    __syncthreads();
  }

  float* outFb = outF ? outF + (size_t)b*bO : nullptr;
  u16*   outBb = outB ? outB + (size_t)b*bO : nullptr;
  const float* nxb = nx ? nx + (size_t)b*NN : nullptr;
  const float* nyb = ny ? ny + (size_t)b*NN : nullptr;
  const float* Cb  = (MODE==MODE_STRUCT) ? Cs + (size_t)b*bO : nullptr;
  const float* mb  = (MODE==MODE_STRUCT) ? mu + (size_t)b*NN : nullptr;
  float lsum = 0.f;
  #pragma unroll
  for(int mi=0;mi<4;mi++){
    #pragma unroll
    for(int j=0;j<4;j++){
      int row = m0 + row_off + mi*16 + q*4 + j;
      float ir = 0.f, mr = 0.f;
      if(MODE==MODE_COST)   ir = 1.f/fmaxf(nxb[row],1e-12f);
      if(MODE==MODE_STRUCT) mr = mb[row];
      #pragma unroll
      for(int ni=0;ni<4;ni++){
        int col = n0 + col_off + ni*16 + loc;
        float v = acc[mi][ni][j];
        if(MODE==MODE_PROJ){
          v += bias[col];
          outBb[(size_t)row*ldo + col] = f2bf(v);
        } else if(MODE==MODE_COST){
          float ic = 1.f/fmaxf(nyb[col],1e-12f);
          v = 1.f - v*ir*ic;
          if(outFb) outFb[(size_t)row*ldo + col] = v;
          if(outBb) outBb[(size_t)row*ldo + col] = f2bf(v);
        } else if(MODE==MODE_PLAIN){
          outBb[(size_t)row*ldo + col] = f2bf(v);
        } else {
          float d = Cb[(size_t)row*ldo + col] - v;
          lsum += d*d*mr*mb[col];
        }
      }
    }
  }
  if(MODE==MODE_STRUCT){
    lsum = wred_sum(lsum);
    if(lane==0) red[w] = lsum;
    __syncthreads();
    if(tid==0) atomicAdd(accp+6, red[0]+red[1]+red[2]+red[3]);
  }
}

// ---------------- bf16 transpose (256x256 per batch) ----------------
__global__ void k_transpose_bf(const u16* __restrict__ Min, u16* __restrict__ Mout){
  int b = blockIdx.z;
  __shared__ u16 t[32][34];
  int i0 = blockIdx.y*32, j0 = blockIdx.x*32;
  int tx = threadIdx.x, ty = threadIdx.y;
  const u16* Mb = Min + (size_t)b*NN*NN;
  u16* Ob = Mout + (size_t)b*NN*NN;
  for(int r=0;r<32;r+=8) t[ty+r][tx] = Mb[(size_t)(i0+ty+r)*NN + j0+tx];
  __syncthreads();
  for(int r=0;r<32;r+=8) Ob[(size_t)(j0+ty+r)*NN + i0+tx] = t[tx][ty+r];
}

// ---------------- fused Sinkhorn: 20 iters + Gamma/feat/Gn epilogue ----------------
// one block per (pass,batch): 128 blocks x 1024 threads. u,v in LDS; base-2 domain.
__global__ __launch_bounds__(1024) void k_sinkhorn_fused(
    const u16* __restrict__ Mbf, const u16* __restrict__ Mtbf,
    const float* __restrict__ logmu2, const float* __restrict__ lognu2,
    u16* __restrict__ Gn, float* __restrict__ accp)
{
  __shared__ float su[NN], sv[NN], slmu[NN], slnu[NN], red[16];
  int b = blockIdx.x;
  const u16* Mb  = Mbf  + (size_t)b*NN*NN;
  const u16* Mtb = Mtbf + (size_t)b*NN*NN;
  int tid = threadIdx.x, w = tid>>6, l = tid&63;
  if(tid < NN){
    su[tid]=0.f; sv[tid]=0.f;
    slmu[tid]=logmu2[(size_t)b*NN+tid];
    slnu[tid]=lognu2[(size_t)b*NN+tid];
  }
  __syncthreads();
  for(int it=0; it<20; it++){
    // u-step: u[r] = logmu2[r] - LSE2_c(-C2*M[r,c] + v[c])
    for(int rr=0; rr<16; rr++){
      int r = (w<<4) + rr;
      ushort4 mv = *(const ushort4*)(Mb + (size_t)r*NN + (l<<2));
      float4 vv = *(const float4*)(sv + (l<<2));
      float x0 = fmaf(-C2LOG, bf2f(mv.x), vv.x);
      float x1 = fmaf(-C2LOG, bf2f(mv.y), vv.y);
      float x2 = fmaf(-C2LOG, bf2f(mv.z), vv.z);
      float x3 = fmaf(-C2LOG, bf2f(mv.w), vv.w);
      float mx = fmaxf(fmaxf(x0,x1),fmaxf(x2,x3));
      mx = wred_max(mx);
      float s = exp2f(x0-mx)+exp2f(x1-mx)+exp2f(x2-mx)+exp2f(x3-mx);
      s = wred_sum(s);
      if(l==0) su[r] = slmu[r] - (mx + __log2f(s));
    }
    __syncthreads();
    // v-step: v[c] = lognu2[c] - LSE2_r(-C2*M[r,c] + u[r])   (via Mt rows)
    for(int rr=0; rr<16; rr++){
      int r = (w<<4) + rr;
      ushort4 mv = *(const ushort4*)(Mtb + (size_t)r*NN + (l<<2));
      float4 uu = *(const float4*)(su + (l<<2));
      float x0 = fmaf(-C2LOG, bf2f(mv.x), uu.x);
      float x1 = fmaf(-C2LOG, bf2f(mv.y), uu.y);
      float x2 = fmaf(-C2LOG, bf2f(mv.z), uu.z);
      float x3 = fmaf(-C2LOG, bf2f(mv.w), uu.w);
      float mx = fmaxf(fmaxf(x0,x1),fmaxf(x2,x3));
      mx = wred_max(mx);
      float s = exp2f(x0-mx)+exp2f(x1-mx)+exp2f(x2-mx)+exp2f(x3-mx);
      s = wred_sum(s);
      if(l==0) sv[r] = slnu[r] - (mx + __log2f(s));
    }
    __syncthreads();
  }
  // epilogue: Gamma = 2^(u - C2*M + v); feat += M*Gamma; Gn = Gamma/rowsum
  float fw = 0.f;
  u16* Gb = Gn + (size_t)b*NN*NN;
  for(int rr=0; rr<16; rr++){
    int r = (w<<4) + rr;
    ushort4 mv = *(const ushort4*)(Mb + (size_t)r*NN + (l<<2));
    float4 vv = *(const float4*)(sv + (l<<2));
    float ur = su[r];
    float m0=bf2f(mv.x), m1=bf2f(mv.y), m2=bf2f(mv.z), m3=bf2f(mv.w);
    float g0 = exp2f(fmaf(-C2LOG,m0,vv.x)+ur);
    float g1 = exp2f(fmaf(-C2LOG,m1,vv.y)+ur);
    float g2 = exp2f(fmaf(-C2LOG,m2,vv.z)+ur);
    float g3 = exp2f(fmaf(-C2LOG,m3,vv.w)+ur);
    float s = g0+g1+g2+g3;
    float f = m0*g0+m1*g1+m2*g2+m3*g3;
    s = wred_sum(s); f = wred_sum(f);
    if(l==0) fw += f;
    float inv = 1.f/(s+1e-8f);
    ushort4 o;
    o.x=f2bf(g0*inv); o.y=f2bf(g1*inv); o.z=f2bf(g2*inv); o.w=f2bf(g3*inv);
    *(ushort4*)(Gb + (size_t)r*NN + (l<<2)) = o;
  }
  if(l==0) red[w]=fw;
  __syncthreads();
  if(tid==0){
    float t=0.f;
    #pragma unroll
    for(int i=0;i<16;i++) t+=red[i];
    atomicAdd(accp+5, t);
  }
}

__global__ void k_final(const float* __restrict__ acc, float* __restrict__ out){
  out[0] = acc[0]
         + 20.f*acc[3]*(1.f/8128.f)
         + 40.f*acc[4]*(1.f/2048256.f)
         + 0.25f*(acc[5]+acc[6])*(1.f/64.f);
}

// ---------------- host ----------------
extern "C" void kernel_launch(void* const* d_in, const int* in_sizes, int n_in,
                              void* d_out, int out_size, void* d_ws, size_t ws_size,
                              hipStream_t stream) {
  const float* s_q_reps   = (const float*)d_in[0];
  const float* s_p_reps   = (const float*)d_in[1];
  const float* t_q_reps   = (const float*)d_in[2];
  const float* t_p_reps   = (const float*)d_in[3];
  const float* s_q_states = (const float*)d_in[4];
  const float* s_p_states = (const float*)d_in[5];
  const float* t_q_states = (const float*)d_in[6];
  const float* t_p_states = (const float*)d_in[7];
  const float* proj_w     = (const float*)d_in[8];
  const float* proj_b     = (const float*)d_in[9];
  float* ws = (float*)d_ws;
  float* acc = ws + OFF_ACC;
  u16* M_BF   = (u16*)(ws + OFF_MBF);
  u16* MT_BF  = (u16*)(ws + OFF_MTBF);
  u16* ZS_BF  = (u16*)(ws + OFF_ZS_BF);
  u16* ZT_BF  = (u16*)(ws + OFF_ZT_BF);
  u16* WT_BF  = (u16*)(ws + OFF_WT_BF);
  u16* ZSP_BF = (u16*)(ws + OFF_ZSP_BF);
  u16* GN_BF  = (u16*)(ws + OFF_GN_BF);
  u16* CT_BF  = (u16*)(ws + OFF_CT_BF);
  u16* T_BF   = (u16*)(ws + OFF_T_BF);

  hipMemsetAsync(acc, 0, 16*sizeof(float), stream);

  // ---- Part A ----
  k_l2norm_rows<<<64,256,0,stream>>>(s_q_reps, ws+OFF_SQ128, 768, 128);
  k_l2norm_rows<<<64,256,0,stream>>>(s_p_reps, ws+OFF_SP128, 768, 128);
  k_l2norm_rows<<<64,256,0,stream>>>(t_q_reps, ws+OFF_TQ128, 768, 128);
  k_l2norm_rows<<<64,256,0,stream>>>(t_p_reps, ws+OFF_TP128, 768, 128);
  k_l2norm_rows<<<64,256,0,stream>>>(s_q_reps, ws+OFF_SQ768, 768, 768);
  k_l2norm_rows<<<64,256,0,stream>>>(s_p_reps, ws+OFF_SP768, 768, 768);
  k_contrastive<<<64,64,0,stream>>>(ws+OFF_SQ128, ws+OFF_SP128, 128, 1.0f, acc);
  k_contrastive<<<64,64,0,stream>>>(ws+OFF_SQ768, ws+OFF_SP768, 768, 2.0f, acc);
  k_gram_ds<<<128,128,0,stream>>>(ws+OFF_SQ128, ws+OFF_TQ128, ws+OFF_DS, ws+OFF_DT, acc);
  k_rkd_dist<<<128,128,0,stream>>>(ws+OFF_DS, ws+OFF_DT, acc);
  k_rkd_angle<<<128,256,65532,stream>>>(ws+OFF_SQ128, ws+OFF_TQ128, ws+OFF_PSI, acc);

  k_wt<<<dim3(HTT/32, HSS/32),dim3(32,8),0,stream>>>(proj_w, WT_BF);

  // ---- Part B phase 1: per-pass GEMMs into doubled buffers ----
  for(int pass=0; pass<2; pass++){
    const float* zs = pass ? s_p_states : s_q_states;
    const float* zt = pass ? t_p_states : t_q_states;
    size_t po  = (size_t)pass*NB*NN*NN;   // per-pass matrix offset
    size_t pr  = (size_t)pass*ROWS;       // per-pass row-vector offset
    k_cvt_norm<<<ROWS,256,0,stream>>>(zs, ZS_BF, ws+OFF_NS, HSS);
    k_cvt_norm<<<ROWS,256,0,stream>>>(zt, ZT_BF, ws+OFF_NT, HTT);
    k_saliency<<<NB,256,0,stream>>>(ws+OFF_NS, ws+OFF_MU+pr, ws+OFF_LOGMU+pr);
    k_saliency<<<NB,256,0,stream>>>(ws+OFF_NT, nullptr,      ws+OFF_LOGNU+pr);
    k_mfma<MODE_PROJ><<<dim3(HTT/128, ROWS/128, 1),256,0,stream>>>(
        ZS_BF, HSS, 0, WT_BF, HSS, 0, HSS,
        nullptr, ZSP_BF, HTT, 0,
        nullptr, nullptr, proj_b, nullptr, nullptr, nullptr);
    k_row_norm_bf16<<<ROWS,256,0,stream>>>(ZSP_BF, ws+OFF_NSP, HTT);
    // C_s (f32)
    k_mfma<MODE_COST><<<dim3(2,2,NB),256,0,stream>>>(
        ZS_BF, HSS, (long)NN*HSS, ZS_BF, HSS, (long)NN*HSS, HSS,
        ws+OFF_CS+po, nullptr, NN, (long)NN*NN,
        ws+OFF_NS, ws+OFF_NS, nullptr, nullptr, nullptr, nullptr);
    // C_t (bf16)
    k_mfma<MODE_COST><<<dim3(2,2,NB),256,0,stream>>>(
        ZT_BF, HTT, (long)NN*HTT, ZT_BF, HTT, (long)NN*HTT, HTT,
        nullptr, CT_BF+po, NN, (long)NN*NN,
        ws+OFF_NT, ws+OFF_NT, nullptr, nullptr, nullptr, nullptr);
    // M (bf16)
    k_mfma<MODE_COST><<<dim3(2,2,NB),256,0,stream>>>(
        ZSP_BF, HTT, (long)NN*HTT, ZT_BF, HTT, (long)NN*HTT, HTT,
        nullptr, M_BF+po, NN, (long)NN*NN,
        ws+OFF_NSP, ws+OFF_NT, nullptr, nullptr, nullptr, nullptr);
  }

  // ---- Part B phase 2: Sinkhorn (both passes in one dispatch) ----
  k_transpose_bf<<<dim3(8,8,2*NB),dim3(32,8),0,stream>>>(M_BF, MT_BF);
  k_sinkhorn_fused<<<2*NB,1024,0,stream>>>(M_BF, MT_BF,
      ws+OFF_LOGMU, ws+OFF_LOGNU, GN_BF, acc);

  // ---- Part B phase 3: T = Gn@Ct, struct loss (batched over both passes) ----
  k_mfma<MODE_PLAIN><<<dim3(2,2,2*NB),256,0,stream>>>(
      GN_BF, NN, (long)NN*NN, CT_BF, NN, (long)NN*NN, NN,
      nullptr, T_BF, NN, (long)NN*NN,
      nullptr, nullptr, nullptr, nullptr, nullptr, nullptr);
  k_mfma<MODE_STRUCT><<<dim3(2,2,2*NB),256,0,stream>>>(
      T_BF, NN, (long)NN*NN, GN_BF, NN, (long)NN*NN, NN,
      nullptr, nullptr, NN, (long)NN*NN,
      nullptr, nullptr, nullptr, ws+OFF_CS, ws+OFF_MU, acc);

  k_final<<<1,1,0,stream>>>(acc, (float*)d_out);
}

// Round 4
// 1440.810 us; speedup vs baseline: 2.0403x; 1.0434x over previous
//
#include <hip/hip_runtime.h>
#include <math.h>

// Problem dims
#define NB   64      // batch B
#define NN   256     // tokens N
#define HSS  768     // H_S
#define HTT  1024    // H_T
#define ROWS (NB*NN) // 16384
#define C2LOG 14.426950408889634f  // 10 * log2(e)  (OT eps=0.1 -> -10*M in exponent)

typedef unsigned short u16;
typedef __attribute__((ext_vector_type(8))) short bf16x8;
typedef __attribute__((ext_vector_type(4))) float f32x4;

// ---------------- workspace layout (float offsets) ----------------
static const size_t OFF_ACC   = 0;                          // 16 floats
static const size_t OFF_SQ128 = 16;
static const size_t OFF_SP128 = OFF_SQ128 + 64*128;
static const size_t OFF_TQ128 = OFF_SP128 + 64*128;
static const size_t OFF_TP128 = OFF_TQ128 + 64*128;
static const size_t OFF_SQ768 = OFF_TP128 + 64*128;
static const size_t OFF_SP768 = OFF_SQ768 + 64*768;
static const size_t OFF_DS    = OFF_SP768 + 64*768;         // 128*128
static const size_t OFF_DT    = OFF_DS + 128*128;
// doubled (both GW passes) f32 C_s
static const size_t OFF_CS    = OFF_DT + 128*128;           // 2*B*N*N f32
static const size_t OFF_PSI   = OFF_CS;                     // ALIAS: Part A only (needs 2.1M < 8.4M)
// bf16 buffers (float units = u16count/2)
static const size_t OFF_MBF   = OFF_CS  + (size_t)2*NB*NN*NN;     // 2*B*N*N bf16
static const size_t OFF_MTBF  = OFF_MBF + (size_t)NB*NN*NN;       // 2*B*N*N bf16
static const size_t OFF_ZS_BF = OFF_MTBF+ (size_t)NB*NN*NN;       // 16384x768 bf16
static const size_t OFF_ZT_BF = OFF_ZS_BF + (size_t)ROWS*HSS/2;   // 16384x1024 bf16
static const size_t OFF_WT_BF = OFF_ZT_BF + (size_t)ROWS*HTT/2;   // 1024x768 bf16
static const size_t OFF_ZSP_BF= OFF_WT_BF + (size_t)HTT*HSS/2;    // 16384x1024 bf16
static const size_t OFF_GN_BF = OFF_ZSP_BF+ (size_t)ROWS*HTT/2;   // 2*B*N*N bf16
static const size_t OFF_CT_BF = OFF_GN_BF + (size_t)NB*NN*NN;     // 2*B*N*N bf16
static const size_t OFF_T_BF  = OFF_ZS_BF;                  // ALIAS: ZS dead after cost GEMMs
static const size_t OFF_NS    = OFF_CT_BF + (size_t)NB*NN*NN;
static const size_t OFF_NT    = OFF_NS + ROWS;
static const size_t OFF_NSP   = OFF_NT + ROWS;
static const size_t OFF_MU    = OFF_NSP + ROWS;             // 2*ROWS
static const size_t OFF_LOGMU = OFF_MU + 2*ROWS;            // 2*ROWS (log2 domain)
static const size_t OFF_LOGNU = OFF_LOGMU + 2*ROWS;         // 2*ROWS (log2 domain)

// acc: 0=contrastive 1=ds_sum 2=dt_sum 3=dist_huber 4=angle_huber 5=feat 6=struct

// ---------------- helpers ----------------
__device__ __forceinline__ float wred_sum(float v){
  #pragma unroll
  for(int o=32;o>0;o>>=1) v += __shfl_xor(v,o,64);
  return v;
}
__device__ __forceinline__ float wred_max(float v){
  #pragma unroll
  for(int o=32;o>0;o>>=1) v = fmaxf(v, __shfl_xor(v,o,64));
  return v;
}
__device__ __forceinline__ u16 f2bf(float f){
  unsigned u = __float_as_uint(f);
  unsigned r = (u + 0x7fffu + ((u>>16)&1u)) >> 16;
  return (u16)r;
}
__device__ __forceinline__ float bf2f(u16 h){
  return __uint_as_float(((unsigned)h)<<16);
}

// ---------------- Part A kernels ----------------
__global__ __launch_bounds__(256) void k_l2norm_rows(const float* __restrict__ in,
    float* __restrict__ out, int k_in, int k_use){
  int r = blockIdx.x;
  const float* row = in + (size_t)r*k_in;
  float ss = 0.f;
  for(int d=threadIdx.x; d<k_use; d+=256){ float x=row[d]; ss += x*x; }
  ss = wred_sum(ss);
  __shared__ float sm[4];
  if((threadIdx.x&63)==0) sm[threadIdx.x>>6]=ss;
  __syncthreads();
  float tot = sm[0]+sm[1]+sm[2]+sm[3];
  float inv = 1.f / fmaxf(sqrtf(tot), 1e-12f);
  for(int d=threadIdx.x; d<k_use; d+=256) out[(size_t)r*k_use + d] = row[d]*inv;
}

__global__ __launch_bounds__(64) void k_contrastive(const float* __restrict__ q,
    const float* __restrict__ p, int dim, float weight, float* __restrict__ acc){
  int i = blockIdx.x, j = threadIdx.x;
  const float* qi = q + (size_t)i*dim;
  const float* pj = p + (size_t)j*dim;
  float dot = 0.f;
  for(int d=0; d<dim; d++) dot += qi[d]*pj[d];
  float s = dot / 0.07f;
  float mx = wred_max(s);
  float e = expf(s - mx);
  float Z = wred_sum(e);
  float logZ = mx + logf(Z);
  float diag = __shfl(s, i, 64);
  if(j==0) atomicAdd(acc+0, weight*(logZ - diag)*(1.f/64.f));
}

__global__ __launch_bounds__(128) void k_gram_ds(const float* __restrict__ sb,
    const float* __restrict__ tb, float* __restrict__ ds, float* __restrict__ dt,
    float* __restrict__ acc){
  int r = blockIdx.x, c = threadIdx.x;
  const float* sr = sb + r*128; const float* sc = sb + c*128;
  const float* tr = tb + r*128; const float* tc = tb + c*128;
  float dot_s=0,ssr=0,ssc=0,dot_t=0,tsr=0,tsc=0;
  for(int d=0; d<128; d++){
    float a=sr[d], b=sc[d]; dot_s += a*b; ssr += a*a; ssc += b*b;
    float at=tr[d], bt=tc[d]; dot_t += at*bt; tsr += at*at; tsc += bt*bt;
  }
  float dv = ssr + ssc - 2.f*dot_s;
  float tv = tsr + tsc - 2.f*dot_t;
  ds[r*128+c] = dv; dt[r*128+c] = tv;
  float ms = (c>r)? dv : 0.f;
  float mt = (c>r)? tv : 0.f;
  ms = wred_sum(ms); mt = wred_sum(mt);
  __shared__ float sm[2][2];
  if((threadIdx.x&63)==0){ sm[0][threadIdx.x>>6]=ms; sm[1][threadIdx.x>>6]=mt; }
  __syncthreads();
  if(threadIdx.x==0){ atomicAdd(acc+1, sm[0][0]+sm[0][1]); atomicAdd(acc+2, sm[1][0]+sm[1][1]); }
}

__global__ __launch_bounds__(128) void k_rkd_dist(const float* __restrict__ ds,
    const float* __restrict__ dt, float* __restrict__ acc){
  int r=blockIdx.x, c=threadIdx.x;
  float mean_s = acc[1]*(1.f/8128.f) + 1e-8f;
  float mean_t = acc[2]*(1.f/8128.f) + 1e-8f;
  float h=0.f;
  if(c>r){
    float diff = ds[r*128+c]/mean_s - dt[r*128+c]/mean_t;
    float a = fabsf(diff);
    h = (a<1.f)? 0.5f*a*a : a-0.5f;
  }
  h = wred_sum(h);
  __shared__ float sm[2];
  if((threadIdx.x&63)==0) sm[threadIdx.x>>6]=h;
  __syncthreads();
  if(threadIdx.x==0) atomicAdd(acc+3, sm[0]+sm[1]);
}

__global__ __launch_bounds__(256) void k_rkd_angle(const float* __restrict__ sb,
    const float* __restrict__ tb, float* __restrict__ psibuf, float* __restrict__ acc){
  extern __shared__ float eLDS[];
  const int j = blockIdx.x;
  const int tid = threadIdx.x;
  float hsum = 0.f;
  for(int pass=0; pass<2; pass++){
    const float* xb = pass ? tb : sb;
    __syncthreads();
    if(tid < 128 && tid != j){
      const int i = tid;
      const int rr = i - (i > j ? 1 : 0);
      const float* xi = xb + i*128;
      const float* xj = xb + j*128;
      float ssq = 0.f;
      for(int d=0; d<128; d++){ float df = xj[d]-xi[d]; ssq += df*df; }
      float inv = 1.f/(sqrtf(ssq)+1e-8f);
      for(int d=0; d<128; d++) eLDS[rr*129+d] = (xj[d]-xi[d])*inv;
    }
    __syncthreads();
    for(int it=0; it<64; it++){
      int p = it*256 + tid;
      int i = p >> 7, k = p & 127;
      bool ok = (i!=j) && (k!=j) && (i!=k);
      float dot = 0.f;
      if(ok){
        const float* ei = eLDS + (size_t)(i-(i>j?1:0))*129;
        const float* ek = eLDS + (size_t)(k-(k>j?1:0))*129;
        for(int d=0; d<128; d++) dot += ei[d]*ek[d];
      }
      if(pass==0){ psibuf[(size_t)j*16384 + p] = dot; }
      else if(ok){
        float diff = psibuf[(size_t)j*16384 + p] - dot;
        float a = fabsf(diff);
        hsum += (a < 1.f) ? 0.5f*a*a : a - 0.5f;
      }
    }
  }
  hsum = wred_sum(hsum);
  if((tid & 63) == 0) atomicAdd(acc + 4, hsum);
}

// ---------------- Part B: convert+norm / saliency ----------------
__global__ __launch_bounds__(256) void k_cvt_norm(const float* __restrict__ in,
    u16* __restrict__ out, float* __restrict__ nrm, int K){
  int r = blockIdx.x;
  const float* row = in + (size_t)r*K;
  u16* orow = out + (size_t)r*K;
  float ss=0.f;
  for(int d=threadIdx.x; d<K; d+=256){ float x=row[d]; ss+=x*x; orow[d]=f2bf(x); }
  ss = wred_sum(ss);
  __shared__ float sm[4];
  if((threadIdx.x&63)==0) sm[threadIdx.x>>6]=ss;
  __syncthreads();
  if(threadIdx.x==0) nrm[r] = sqrtf(sm[0]+sm[1]+sm[2]+sm[3]);
}

__global__ __launch_bounds__(256) void k_row_norm_bf16(const u16* __restrict__ z,
    float* __restrict__ nrm, int K){
  int r = blockIdx.x;
  const u16* row = z + (size_t)r*K;
  float ss=0.f;
  for(int d=threadIdx.x; d<K; d+=256){ float x=bf2f(row[d]); ss+=x*x; }
  ss = wred_sum(ss);
  __shared__ float sm[4];
  if((threadIdx.x&63)==0) sm[threadIdx.x>>6]=ss;
  __syncthreads();
  if(threadIdx.x==0) nrm[r] = sqrtf(sm[0]+sm[1]+sm[2]+sm[3]);
}

// W (HSS x HTT) f32 -> Wt (HTT x HSS) bf16
__global__ void k_wt(const float* __restrict__ W, u16* __restrict__ Wt){
  __shared__ float t[32][33];
  int k0 = blockIdx.y*32, n0 = blockIdx.x*32;
  int tx = threadIdx.x, ty = threadIdx.y;
  for(int r=0;r<32;r+=8) t[ty+r][tx] = W[(size_t)(k0+ty+r)*HTT + n0+tx];
  __syncthreads();
  for(int r=0;r<32;r+=8) Wt[(size_t)(n0+ty+r)*HSS + k0+tx] = f2bf(t[tx][ty+r]);
}

// softmax over N; logmu emitted in LOG2 domain (for exp2-based Sinkhorn)
__global__ __launch_bounds__(256) void k_saliency(const float* __restrict__ nrm,
    float* __restrict__ mu, float* __restrict__ logmu2){
  int b = blockIdx.x, n = threadIdx.x;
  float x = nrm[b*NN+n];
  float mx = wred_max(x);
  __shared__ float sm[4], sm2[4];
  if((n&63)==0) sm[n>>6]=mx;
  __syncthreads();
  mx = fmaxf(fmaxf(sm[0],sm[1]),fmaxf(sm[2],sm[3]));
  float e = expf(x-mx);
  float s = wred_sum(e);
  if((n&63)==0) sm2[n>>6]=s;
  __syncthreads();
  s = sm2[0]+sm2[1]+sm2[2]+sm2[3];
  float m = e/s;
  if(mu) mu[b*NN+n]=m;
  logmu2[b*NN+n]=log2f(m+1e-8f);
}

// ---------------- MFMA GEMM (NT form) ----------------
enum { MODE_PROJ=0, MODE_COST=1, MODE_PLAIN=2, MODE_STRUCT=3 };

template<int MODE>
__global__ __launch_bounds__(256) void k_mfma(
    const u16* __restrict__ A, int lda, long bA,
    const u16* __restrict__ B, int ldb, long bB,
    int K,
    float* __restrict__ outF, u16* __restrict__ outB, int ldo, long bO,
    const float* __restrict__ nx, const float* __restrict__ ny,
    const float* __restrict__ bias,
    const float* __restrict__ Cs, const float* __restrict__ mu,
    float* __restrict__ accp)
{
  __shared__ u16 As[128*32];
  __shared__ u16 Bs[128*32];
  __shared__ float red[4];
  int b = blockIdx.z;
  const u16* Ab = A + (size_t)b*bA;
  const u16* Bb = B + (size_t)b*bB;
  int tid = threadIdx.x;
  int lane = tid & 63, w = tid >> 6;
  int m0 = blockIdx.y*128, n0 = blockIdx.x*128;
  int row_off = (w>>1)*64, col_off = (w&1)*64;
  int q = lane>>4, loc = lane&15;
  f32x4 acc[4][4] = {};
  int srow = tid >> 2;
  int skc  = tid & 3;

  for(int k0=0;k0<K;k0+=32){
    #pragma unroll
    for(int h=0;h<2;h++){
      int row = srow + h*64;
      int slot = skc ^ ((row>>1)&3);
      uint4 av = *(const uint4*)(Ab + (size_t)(m0+row)*lda + k0 + skc*8);
      uint4 bv = *(const uint4*)(Bb + (size_t)(n0+row)*ldb + k0 + skc*8);
      *(uint4*)(As + row*32 + slot*8) = av;
      *(uint4*)(Bs + row*32 + slot*8) = bv;
    }
    __syncthreads();
    bf16x8 af[4], bfr[4];
    #pragma unroll
    for(int mi=0;mi<4;mi++){
      int r = row_off + mi*16 + loc;
      int slot = q ^ ((r>>1)&3);
      af[mi] = *(const bf16x8*)(As + r*32 + slot*8);
    }
    #pragma unroll
    for(int ni=0;ni<4;ni++){
      int r = col_off + ni*16 + loc;
      int slot = q ^ ((r>>1)&3);
      bfr[ni] = *(const bf16x8*)(Bs + r*32 + slot*8);
    }
    #pragma unroll
    for(int mi=0;mi<4;mi++)
      #pragma unroll
      for(int ni=0;ni<4;ni++)
        acc[mi][ni] = __builtin_amdgcn_mfma_f32_16x16x32_bf16(af[mi], bfr[ni], acc[mi][ni], 0,0,0);
    __syncthreads();
  }

  float* outFb = outF ? outF + (size_t)b*bO : nullptr;
  u16*   outBb = outB ? outB + (size_t)b*bO : nullptr;
  const float* nxb = nx ? nx + (size_t)b*NN : nullptr;
  const float* nyb = ny ? ny + (size_t)b*NN : nullptr;
  const float* Cb  = (MODE==MODE_STRUCT) ? Cs + (size_t)b*bO : nullptr;
  const float* mb  = (MODE==MODE_STRUCT) ? mu + (size_t)b*NN : nullptr;
  float lsum = 0.f;
  #pragma unroll
  for(int mi=0;mi<4;mi++){
    #pragma unroll
    for(int j=0;j<4;j++){
      int row = m0 + row_off + mi*16 + q*4 + j;
      float ir = 0.f, mr = 0.f;
      if(MODE==MODE_COST)   ir = 1.f/fmaxf(nxb[row],1e-12f);
      if(MODE==MODE_STRUCT) mr = mb[row];
      #pragma unroll
      for(int ni=0;ni<4;ni++){
        int col = n0 + col_off + ni*16 + loc;
        float v = acc[mi][ni][j];
        if(MODE==MODE_PROJ){
          v += bias[col];
          outBb[(size_t)row*ldo + col] = f2bf(v);
        } else if(MODE==MODE_COST){
          float ic = 1.f/fmaxf(nyb[col],1e-12f);
          v = 1.f - v*ir*ic;
          if(outFb) outFb[(size_t)row*ldo + col] = v;
          if(outBb) outBb[(size_t)row*ldo + col] = f2bf(v);
        } else if(MODE==MODE_PLAIN){
          outBb[(size_t)row*ldo + col] = f2bf(v);
        } else {
          float d = Cb[(size_t)row*ldo + col] - v;
          lsum += d*d*mr*mb[col];
        }
      }
    }
  }
  if(MODE==MODE_STRUCT){
    lsum = wred_sum(lsum);
    if(lane==0) red[w] = lsum;
    __syncthreads();
    if(tid==0) atomicAdd(accp+6, red[0]+red[1]+red[2]+red[3]);
  }
}

// ---------------- bf16 transpose (256x256 per batch) ----------------
__global__ void k_transpose_bf(const u16* __restrict__ Min, u16* __restrict__ Mout){
  int b = blockIdx.z;
  __shared__ u16 t[32][34];
  int i0 = blockIdx.y*32, j0 = blockIdx.x*32;
  int tx = threadIdx.x, ty = threadIdx.y;
  const u16* Mb = Min + (size_t)b*NN*NN;
  u16* Ob = Mout + (size_t)b*NN*NN;
  for(int r=0;r<32;r+=8) t[ty+r][tx] = Mb[(size_t)(i0+ty+r)*NN + j0+tx];
  __syncthreads();
  for(int r=0;r<32;r+=8) Ob[(size_t)(j0+ty+r)*NN + i0+tx] = t[tx][ty+r];
}

// ---------------- fused Sinkhorn: thread-per-row, register LSE, no shuffles --------
// one block per (pass,batch): 128 blocks x 256 threads. u,v in LDS; base-2 domain.
// No max-subtraction: exponents provably bounded (|x|<~60), f32 range is plenty.
// u-step reads Mt (lane r reads Mt[c*NN+r] -> coalesced); v-step reads M (coalesced).
__global__ __launch_bounds__(256) void k_sinkhorn_fused(
    const u16* __restrict__ Mbf, const u16* __restrict__ Mtbf,
    const float* __restrict__ logmu2, const float* __restrict__ lognu2,
    u16* __restrict__ Gn, float* __restrict__ accp)
{
  __shared__ float su[NN], sv[NN], slmu[NN], slnu[NN], red[4];
  int b = blockIdx.x;
  const u16* Mb  = Mbf  + (size_t)b*NN*NN;
  const u16* Mtb = Mtbf + (size_t)b*NN*NN;
  int tid = threadIdx.x;
  float lmu = logmu2[(size_t)b*NN+tid];
  float lnu = lognu2[(size_t)b*NN+tid];
  su[tid]=0.f; sv[tid]=0.f; slmu[tid]=lmu; slnu[tid]=lnu;
  __syncthreads();
  for(int it=0; it<20; it++){
    // u-step: u[r] = logmu2[r] - log2(sum_c 2^(-C2*M[r,c] + v[c]))
    {
      float s0=0.f,s1=0.f,s2=0.f,s3=0.f;
      #pragma unroll 2
      for(int c=0;c<NN;c+=4){
        float x0 = fmaf(-C2LOG, bf2f(Mtb[(size_t)(c+0)*NN + tid]), sv[c+0]);
        float x1 = fmaf(-C2LOG, bf2f(Mtb[(size_t)(c+1)*NN + tid]), sv[c+1]);
        float x2 = fmaf(-C2LOG, bf2f(Mtb[(size_t)(c+2)*NN + tid]), sv[c+2]);
        float x3 = fmaf(-C2LOG, bf2f(Mtb[(size_t)(c+3)*NN + tid]), sv[c+3]);
        s0 += exp2f(x0); s1 += exp2f(x1); s2 += exp2f(x2); s3 += exp2f(x3);
      }
      float s = (s0+s1)+(s2+s3);
      float unew = lmu - __log2f(s);
      __syncthreads();
      su[tid] = unew;
      __syncthreads();
    }
    // v-step: v[c] = lognu2[c] - log2(sum_r 2^(-C2*M[r,c] + u[r]))
    {
      float s0=0.f,s1=0.f,s2=0.f,s3=0.f;
      #pragma unroll 2
      for(int r=0;r<NN;r+=4){
        float x0 = fmaf(-C2LOG, bf2f(Mb[(size_t)(r+0)*NN + tid]), su[r+0]);
        float x1 = fmaf(-C2LOG, bf2f(Mb[(size_t)(r+1)*NN + tid]), su[r+1]);
        float x2 = fmaf(-C2LOG, bf2f(Mb[(size_t)(r+2)*NN + tid]), su[r+2]);
        float x3 = fmaf(-C2LOG, bf2f(Mb[(size_t)(r+3)*NN + tid]), su[r+3]);
        s0 += exp2f(x0); s1 += exp2f(x1); s2 += exp2f(x2); s3 += exp2f(x3);
      }
      float s = (s0+s1)+(s2+s3);
      float vnew = lnu - __log2f(s);
      __syncthreads();
      sv[tid] = vnew;
      __syncthreads();
    }
  }
  // epilogue: Gamma = 2^(u - C2*M + v); feat += M*Gamma; Gn = Gamma/rowsum
  // wave-per-row-chunk, coalesced ushort4 reads of M rows.
  int w = tid>>6, l = tid&63;
  float fw = 0.f;
  u16* Gb = Gn + (size_t)b*NN*NN;
  for(int rr=0; rr<64; rr++){
    int r = (w<<6) + rr;
    ushort4 mv = *(const ushort4*)(Mb + (size_t)r*NN + (l<<2));
    float4 vv = *(const float4*)(sv + (l<<2));
    float ur = su[r];
    float m0=bf2f(mv.x), m1=bf2f(mv.y), m2=bf2f(mv.z), m3=bf2f(mv.w);
    float g0 = exp2f(fmaf(-C2LOG,m0,vv.x)+ur);
    float g1 = exp2f(fmaf(-C2LOG,m1,vv.y)+ur);
    float g2 = exp2f(fmaf(-C2LOG,m2,vv.z)+ur);
    float g3 = exp2f(fmaf(-C2LOG,m3,vv.w)+ur);
    float s = g0+g1+g2+g3;
    float f = m0*g0+m1*g1+m2*g2+m3*g3;
    s = wred_sum(s); f = wred_sum(f);
    if(l==0) fw += f;
    float inv = 1.f/(s+1e-8f);
    ushort4 o;
    o.x=f2bf(g0*inv); o.y=f2bf(g1*inv); o.z=f2bf(g2*inv); o.w=f2bf(g3*inv);
    *(ushort4*)(Gb + (size_t)r*NN + (l<<2)) = o;
  }
  if(l==0) red[w]=fw;
  __syncthreads();
  if(tid==0){
    atomicAdd(accp+5, red[0]+red[1]+red[2]+red[3]);
  }
}

__global__ void k_final(const float* __restrict__ acc, float* __restrict__ out){
  out[0] = acc[0]
         + 20.f*acc[3]*(1.f/8128.f)
         + 40.f*acc[4]*(1.f/2048256.f)
         + 0.25f*(acc[5]+acc[6])*(1.f/64.f);
}

// ---------------- host ----------------
extern "C" void kernel_launch(void* const* d_in, const int* in_sizes, int n_in,
                              void* d_out, int out_size, void* d_ws, size_t ws_size,
                              hipStream_t stream) {
  const float* s_q_reps   = (const float*)d_in[0];
  const float* s_p_reps   = (const float*)d_in[1];
  const float* t_q_reps   = (const float*)d_in[2];
  const float* t_p_reps   = (const float*)d_in[3];
  const float* s_q_states = (const float*)d_in[4];
  const float* s_p_states = (const float*)d_in[5];
  const float* t_q_states = (const float*)d_in[6];
  const float* t_p_states = (const float*)d_in[7];
  const float* proj_w     = (const float*)d_in[8];
  const float* proj_b     = (const float*)d_in[9];
  float* ws = (float*)d_ws;
  float* acc = ws + OFF_ACC;
  u16* M_BF   = (u16*)(ws + OFF_MBF);
  u16* MT_BF  = (u16*)(ws + OFF_MTBF);
  u16* ZS_BF  = (u16*)(ws + OFF_ZS_BF);
  u16* ZT_BF  = (u16*)(ws + OFF_ZT_BF);
  u16* WT_BF  = (u16*)(ws + OFF_WT_BF);
  u16* ZSP_BF = (u16*)(ws + OFF_ZSP_BF);
  u16* GN_BF  = (u16*)(ws + OFF_GN_BF);
  u16* CT_BF  = (u16*)(ws + OFF_CT_BF);
  u16* T_BF   = (u16*)(ws + OFF_T_BF);

  hipMemsetAsync(acc, 0, 16*sizeof(float), stream);

  // ---- Part A ----
  k_l2norm_rows<<<64,256,0,stream>>>(s_q_reps, ws+OFF_SQ128, 768, 128);
  k_l2norm_rows<<<64,256,0,stream>>>(s_p_reps, ws+OFF_SP128, 768, 128);
  k_l2norm_rows<<<64,256,0,stream>>>(t_q_reps, ws+OFF_TQ128, 768, 128);
  k_l2norm_rows<<<64,256,0,stream>>>(t_p_reps, ws+OFF_TP128, 768, 128);
  k_l2norm_rows<<<64,256,0,stream>>>(s_q_reps, ws+OFF_SQ768, 768, 768);
  k_l2norm_rows<<<64,256,0,stream>>>(s_p_reps, ws+OFF_SP768, 768, 768);
  k_contrastive<<<64,64,0,stream>>>(ws+OFF_SQ128, ws+OFF_SP128, 128, 1.0f, acc);
  k_contrastive<<<64,64,0,stream>>>(ws+OFF_SQ768, ws+OFF_SP768, 768, 2.0f, acc);
  k_gram_ds<<<128,128,0,stream>>>(ws+OFF_SQ128, ws+OFF_TQ128, ws+OFF_DS, ws+OFF_DT, acc);
  k_rkd_dist<<<128,128,0,stream>>>(ws+OFF_DS, ws+OFF_DT, acc);
  k_rkd_angle<<<128,256,65532,stream>>>(ws+OFF_SQ128, ws+OFF_TQ128, ws+OFF_PSI, acc);

  k_wt<<<dim3(HTT/32, HSS/32),dim3(32,8),0,stream>>>(proj_w, WT_BF);

  // ---- Part B phase 1: per-pass GEMMs into doubled buffers ----
  for(int pass=0; pass<2; pass++){
    const float* zs = pass ? s_p_states : s_q_states;
    const float* zt = pass ? t_p_states : t_q_states;
    size_t po  = (size_t)pass*NB*NN*NN;   // per-pass matrix offset
    size_t pr  = (size_t)pass*ROWS;       // per-pass row-vector offset
    k_cvt_norm<<<ROWS,256,0,stream>>>(zs, ZS_BF, ws+OFF_NS, HSS);
    k_cvt_norm<<<ROWS,256,0,stream>>>(zt, ZT_BF, ws+OFF_NT, HTT);
    k_saliency<<<NB,256,0,stream>>>(ws+OFF_NS, ws+OFF_MU+pr, ws+OFF_LOGMU+pr);
    k_saliency<<<NB,256,0,stream>>>(ws+OFF_NT, nullptr,      ws+OFF_LOGNU+pr);
    k_mfma<MODE_PROJ><<<dim3(HTT/128, ROWS/128, 1),256,0,stream>>>(
        ZS_BF, HSS, 0, WT_BF, HSS, 0, HSS,
        nullptr, ZSP_BF, HTT, 0,
        nullptr, nullptr, proj_b, nullptr, nullptr, nullptr);
    k_row_norm_bf16<<<ROWS,256,0,stream>>>(ZSP_BF, ws+OFF_NSP, HTT);
    // C_s (f32)
    k_mfma<MODE_COST><<<dim3(2,2,NB),256,0,stream>>>(
        ZS_BF, HSS, (long)NN*HSS, ZS_BF, HSS, (long)NN*HSS, HSS,
        ws+OFF_CS+po, nullptr, NN, (long)NN*NN,
        ws+OFF_NS, ws+OFF_NS, nullptr, nullptr, nullptr, nullptr);
    // C_t (bf16)
    k_mfma<MODE_COST><<<dim3(2,2,NB),256,0,stream>>>(
        ZT_BF, HTT, (long)NN*HTT, ZT_BF, HTT, (long)NN*HTT, HTT,
        nullptr, CT_BF+po, NN, (long)NN*NN,
        ws+OFF_NT, ws+OFF_NT, nullptr, nullptr, nullptr, nullptr);
    // M (bf16)
    k_mfma<MODE_COST><<<dim3(2,2,NB),256,0,stream>>>(
        ZSP_BF, HTT, (long)NN*HTT, ZT_BF, HTT, (long)NN*HTT, HTT,
        nullptr, M_BF+po, NN, (long)NN*NN,
        ws+OFF_NSP, ws+OFF_NT, nullptr, nullptr, nullptr, nullptr);
  }

  // ---- Part B phase 2: Sinkhorn (both passes in one dispatch) ----
  k_transpose_bf<<<dim3(8,8,2*NB),dim3(32,8),0,stream>>>(M_BF, MT_BF);
  k_sinkhorn_fused<<<2*NB,256,0,stream>>>(M_BF, MT_BF,
      ws+OFF_LOGMU, ws+OFF_LOGNU, GN_BF, acc);

  // ---- Part B phase 3: T = Gn@Ct, struct loss (batched over both passes) ----
  k_mfma<MODE_PLAIN><<<dim3(2,2,2*NB),256,0,stream>>>(
      GN_BF, NN, (long)NN*NN, CT_BF, NN, (long)NN*NN, NN,
      nullptr, T_BF, NN, (long)NN*NN,
      nullptr, nullptr, nullptr, nullptr, nullptr, nullptr);
  k_mfma<MODE_STRUCT><<<dim3(2,2,2*NB),256,0,stream>>>(
      T_BF, NN, (long)NN*NN, GN_BF, NN, (long)NN*NN, NN,
      nullptr, nullptr, NN, (long)NN*NN,
      nullptr, nullptr, nullptr, ws+OFF_CS, ws+OFF_MU, acc);

  k_final<<<1,1,0,stream>>>(acc, (float*)d_out);
}

// Round 5
// 985.557 us; speedup vs baseline: 2.9827x; 1.4619x over previous
//
#include <hip/hip_runtime.h>
#include <math.h>

// Problem dims
#define NB   64      // batch B
#define NN   256     // tokens N
#define HSS  768     // H_S
#define HTT  1024    // H_T
#define ROWS (NB*NN) // 16384
#define C2LOG 14.426950408889634f  // 10 * log2(e)

typedef unsigned short u16;
typedef __attribute__((ext_vector_type(8))) short bf16x8;
typedef __attribute__((ext_vector_type(4))) float f32x4;

// swizzled LDS index for K[r][c]: chunk rotation keeps both row-reads and
// scattered-row reads conflict-free. granularity: 8 u16 = 16 B.
#define LIDX(r,c) (((r)<<8) + (((((c)>>3) + (r)) & 31)<<3) + ((c)&7))

// ---------------- workspace layout (float offsets) ----------------
static const size_t OFF_ACC   = 0;                          // 16 floats
static const size_t OFF_SQ128 = 16;
static const size_t OFF_SP128 = OFF_SQ128 + 64*128;
static const size_t OFF_TQ128 = OFF_SP128 + 64*128;
static const size_t OFF_TP128 = OFF_TQ128 + 64*128;
static const size_t OFF_SQ768 = OFF_TP128 + 64*128;
static const size_t OFF_SP768 = OFF_SQ768 + 64*768;
static const size_t OFF_DS    = OFF_SP768 + 64*768;         // 128*128
static const size_t OFF_DT    = OFF_DS + 128*128;
static const size_t OFF_CS    = OFF_DT + 128*128;           // 2*B*N*N f32
static const size_t OFF_PSI   = OFF_CS;                     // ALIAS: Part A only
static const size_t OFF_MBF   = OFF_CS  + (size_t)2*NB*NN*NN;     // 2*B*N*N bf16
static const size_t OFF_ZS_BF = OFF_MBF + (size_t)NB*NN*NN;       // 16384x768 bf16
static const size_t OFF_ZT_BF = OFF_ZS_BF + (size_t)ROWS*HSS/2;   // 16384x1024 bf16
static const size_t OFF_WT_BF = OFF_ZT_BF + (size_t)ROWS*HTT/2;   // 1024x768 bf16
static const size_t OFF_ZSP_BF= OFF_WT_BF + (size_t)HTT*HSS/2;    // 16384x1024 bf16
static const size_t OFF_GN_BF = OFF_ZSP_BF+ (size_t)ROWS*HTT/2;   // 2*B*N*N bf16
static const size_t OFF_CT_BF = OFF_GN_BF + (size_t)NB*NN*NN;     // 2*B*N*N bf16
static const size_t OFF_T_BF  = OFF_ZS_BF;                  // ALIAS: ZS dead after cost GEMMs
static const size_t OFF_NS    = OFF_CT_BF + (size_t)NB*NN*NN;
static const size_t OFF_NT    = OFF_NS + ROWS;
static const size_t OFF_NSP   = OFF_NT + ROWS;
static const size_t OFF_MU    = OFF_NSP + ROWS;             // 2*ROWS (linear)
static const size_t OFF_NU    = OFF_MU + 2*ROWS;            // 2*ROWS (linear)

// acc: 0=contrastive 1=ds_sum 2=dt_sum 3=dist_huber 4=angle_huber 5=feat 6=struct

// ---------------- helpers ----------------
__device__ __forceinline__ float wred_sum(float v){
  #pragma unroll
  for(int o=32;o>0;o>>=1) v += __shfl_xor(v,o,64);
  return v;
}
__device__ __forceinline__ float wred_max(float v){
  #pragma unroll
  for(int o=32;o>0;o>>=1) v = fmaxf(v, __shfl_xor(v,o,64));
  return v;
}
__device__ __forceinline__ u16 f2bf(float f){
  unsigned u = __float_as_uint(f);
  unsigned r = (u + 0x7fffu + ((u>>16)&1u)) >> 16;
  return (u16)r;
}
__device__ __forceinline__ float bf2f(u16 h){
  return __uint_as_float(((unsigned)h)<<16);
}

// ---------------- Part A kernels ----------------
__global__ __launch_bounds__(256) void k_l2norm_rows(const float* __restrict__ in,
    float* __restrict__ out, int k_in, int k_use){
  int r = blockIdx.x;
  const float* row = in + (size_t)r*k_in;
  float ss = 0.f;
  for(int d=threadIdx.x; d<k_use; d+=256){ float x=row[d]; ss += x*x; }
  ss = wred_sum(ss);
  __shared__ float sm[4];
  if((threadIdx.x&63)==0) sm[threadIdx.x>>6]=ss;
  __syncthreads();
  float tot = sm[0]+sm[1]+sm[2]+sm[3];
  float inv = 1.f / fmaxf(sqrtf(tot), 1e-12f);
  for(int d=threadIdx.x; d<k_use; d+=256) out[(size_t)r*k_use + d] = row[d]*inv;
}

__global__ __launch_bounds__(64) void k_contrastive(const float* __restrict__ q,
    const float* __restrict__ p, int dim, float weight, float* __restrict__ acc){
  int i = blockIdx.x, j = threadIdx.x;
  const float* qi = q + (size_t)i*dim;
  const float* pj = p + (size_t)j*dim;
  float dot = 0.f;
  for(int d=0; d<dim; d++) dot += qi[d]*pj[d];
  float s = dot / 0.07f;
  float mx = wred_max(s);
  float e = expf(s - mx);
  float Z = wred_sum(e);
  float logZ = mx + logf(Z);
  float diag = __shfl(s, i, 64);
  if(j==0) atomicAdd(acc+0, weight*(logZ - diag)*(1.f/64.f));
}

__global__ __launch_bounds__(128) void k_gram_ds(const float* __restrict__ sb,
    const float* __restrict__ tb, float* __restrict__ ds, float* __restrict__ dt,
    float* __restrict__ acc){
  int r = blockIdx.x, c = threadIdx.x;
  const float* sr = sb + r*128; const float* sc = sb + c*128;
  const float* tr = tb + r*128; const float* tc = tb + c*128;
  float dot_s=0,ssr=0,ssc=0,dot_t=0,tsr=0,tsc=0;
  for(int d=0; d<128; d++){
    float a=sr[d], b=sc[d]; dot_s += a*b; ssr += a*a; ssc += b*b;
    float at=tr[d], bt=tc[d]; dot_t += at*bt; tsr += at*at; tsc += bt*bt;
  }
  float dv = ssr + ssc - 2.f*dot_s;
  float tv = tsr + tsc - 2.f*dot_t;
  ds[r*128+c] = dv; dt[r*128+c] = tv;
  float ms = (c>r)? dv : 0.f;
  float mt = (c>r)? tv : 0.f;
  ms = wred_sum(ms); mt = wred_sum(mt);
  __shared__ float sm[2][2];
  if((threadIdx.x&63)==0){ sm[0][threadIdx.x>>6]=ms; sm[1][threadIdx.x>>6]=mt; }
  __syncthreads();
  if(threadIdx.x==0){ atomicAdd(acc+1, sm[0][0]+sm[0][1]); atomicAdd(acc+2, sm[1][0]+sm[1][1]); }
}

__global__ __launch_bounds__(128) void k_rkd_dist(const float* __restrict__ ds,
    const float* __restrict__ dt, float* __restrict__ acc){
  int r=blockIdx.x, c=threadIdx.x;
  float mean_s = acc[1]*(1.f/8128.f) + 1e-8f;
  float mean_t = acc[2]*(1.f/8128.f) + 1e-8f;
  float h=0.f;
  if(c>r){
    float diff = ds[r*128+c]/mean_s - dt[r*128+c]/mean_t;
    float a = fabsf(diff);
    h = (a<1.f)? 0.5f*a*a : a-0.5f;
  }
  h = wred_sum(h);
  __shared__ float sm[2];
  if((threadIdx.x&63)==0) sm[threadIdx.x>>6]=h;
  __syncthreads();
  if(threadIdx.x==0) atomicAdd(acc+3, sm[0]+sm[1]);
}

__global__ __launch_bounds__(256) void k_rkd_angle(const float* __restrict__ sb,
    const float* __restrict__ tb, float* __restrict__ psibuf, float* __restrict__ acc){
  extern __shared__ float eLDS[];
  const int j = blockIdx.x;
  const int tid = threadIdx.x;
  float hsum = 0.f;
  for(int pass=0; pass<2; pass++){
    const float* xb = pass ? tb : sb;
    __syncthreads();
    if(tid < 128 && tid != j){
      const int i = tid;
      const int rr = i - (i > j ? 1 : 0);
      const float* xi = xb + i*128;
      const float* xj = xb + j*128;
      float ssq = 0.f;
      for(int d=0; d<128; d++){ float df = xj[d]-xi[d]; ssq += df*df; }
      float inv = 1.f/(sqrtf(ssq)+1e-8f);
      for(int d=0; d<128; d++) eLDS[rr*129+d] = (xj[d]-xi[d])*inv;
    }
    __syncthreads();
    for(int it=0; it<64; it++){
      int p = it*256 + tid;
      int i = p >> 7, k = p & 127;
      bool ok = (i!=j) && (k!=j) && (i!=k);
      float dot = 0.f;
      if(ok){
        const float* ei = eLDS + (size_t)(i-(i>j?1:0))*129;
        const float* ek = eLDS + (size_t)(k-(k>j?1:0))*129;
        for(int d=0; d<128; d++) dot += ei[d]*ek[d];
      }
      if(pass==0){ psibuf[(size_t)j*16384 + p] = dot; }
      else if(ok){
        float diff = psibuf[(size_t)j*16384 + p] - dot;
        float a = fabsf(diff);
        hsum += (a < 1.f) ? 0.5f*a*a : a - 0.5f;
      }
    }
  }
  hsum = wred_sum(hsum);
  if((tid & 63) == 0) atomicAdd(acc + 4, hsum);
}

// ---------------- Part B: convert+norm / saliency ----------------
__global__ __launch_bounds__(256) void k_cvt_norm(const float* __restrict__ in,
    u16* __restrict__ out, float* __restrict__ nrm, int K){
  int r = blockIdx.x;
  const float* row = in + (size_t)r*K;
  u16* orow = out + (size_t)r*K;
  float ss=0.f;
  for(int d=threadIdx.x; d<K; d+=256){ float x=row[d]; ss+=x*x; orow[d]=f2bf(x); }
  ss = wred_sum(ss);
  __shared__ float sm[4];
  if((threadIdx.x&63)==0) sm[threadIdx.x>>6]=ss;
  __syncthreads();
  if(threadIdx.x==0) nrm[r] = sqrtf(sm[0]+sm[1]+sm[2]+sm[3]);
}

__global__ __launch_bounds__(256) void k_row_norm_bf16(const u16* __restrict__ z,
    float* __restrict__ nrm, int K){
  int r = blockIdx.x;
  const u16* row = z + (size_t)r*K;
  float ss=0.f;
  for(int d=threadIdx.x; d<K; d+=256){ float x=bf2f(row[d]); ss+=x*x; }
  ss = wred_sum(ss);
  __shared__ float sm[4];
  if((threadIdx.x&63)==0) sm[threadIdx.x>>6]=ss;
  __syncthreads();
  if(threadIdx.x==0) nrm[r] = sqrtf(sm[0]+sm[1]+sm[2]+sm[3]);
}

// W (HSS x HTT) f32 -> Wt (HTT x HSS) bf16
__global__ void k_wt(const float* __restrict__ W, u16* __restrict__ Wt){
  __shared__ float t[32][33];
  int k0 = blockIdx.y*32, n0 = blockIdx.x*32;
  int tx = threadIdx.x, ty = threadIdx.y;
  for(int r=0;r<32;r+=8) t[ty+r][tx] = W[(size_t)(k0+ty+r)*HTT + n0+tx];
  __syncthreads();
  for(int r=0;r<32;r+=8) Wt[(size_t)(n0+ty+r)*HSS + k0+tx] = f2bf(t[tx][ty+r]);
}

// softmax over N (linear output)
__global__ __launch_bounds__(256) void k_saliency(const float* __restrict__ nrm,
    float* __restrict__ out){
  int b = blockIdx.x, n = threadIdx.x;
  float x = nrm[b*NN+n];
  float mx = wred_max(x);
  __shared__ float sm[4], sm2[4];
  if((n&63)==0) sm[n>>6]=mx;
  __syncthreads();
  mx = fmaxf(fmaxf(sm[0],sm[1]),fmaxf(sm[2],sm[3]));
  float e = expf(x-mx);
  float s = wred_sum(e);
  if((n&63)==0) sm2[n>>6]=s;
  __syncthreads();
  s = sm2[0]+sm2[1]+sm2[2]+sm2[3];
  out[b*NN+n] = e/s;
}

// ---------------- MFMA GEMM (NT form) ----------------
enum { MODE_PROJ=0, MODE_COST=1, MODE_PLAIN=2, MODE_STRUCT=3 };

template<int MODE>
__global__ __launch_bounds__(256) void k_mfma(
    const u16* __restrict__ A, int lda, long bA,
    const u16* __restrict__ B, int ldb, long bB,
    int K,
    float* __restrict__ outF, u16* __restrict__ outB, int ldo, long bO,
    const float* __restrict__ nx, const float* __restrict__ ny,
    const float* __restrict__ bias,
    const float* __restrict__ Cs, const float* __restrict__ mu,
    float* __restrict__ accp)
{
  __shared__ u16 As[128*32];
  __shared__ u16 Bs[128*32];
  __shared__ float red[4];
  int b = blockIdx.z;
  const u16* Ab = A + (size_t)b*bA;
  const u16* Bb = B + (size_t)b*bB;
  int tid = threadIdx.x;
  int lane = tid & 63, w = tid >> 6;
  int m0 = blockIdx.y*128, n0 = blockIdx.x*128;
  int row_off = (w>>1)*64, col_off = (w&1)*64;
  int q = lane>>4, loc = lane&15;
  f32x4 acc[4][4] = {};
  int srow = tid >> 2;
  int skc  = tid & 3;

  for(int k0=0;k0<K;k0+=32){
    #pragma unroll
    for(int h=0;h<2;h++){
      int row = srow + h*64;
      int slot = skc ^ ((row>>1)&3);
      uint4 av = *(const uint4*)(Ab + (size_t)(m0+row)*lda + k0 + skc*8);
      uint4 bv = *(const uint4*)(Bb + (size_t)(n0+row)*ldb + k0 + skc*8);
      *(uint4*)(As + row*32 + slot*8) = av;
      *(uint4*)(Bs + row*32 + slot*8) = bv;
    }
    __syncthreads();
    bf16x8 af[4], bfr[4];
    #pragma unroll
    for(int mi=0;mi<4;mi++){
      int r = row_off + mi*16 + loc;
      int slot = q ^ ((r>>1)&3);
      af[mi] = *(const bf16x8*)(As + r*32 + slot*8);
    }
    #pragma unroll
    for(int ni=0;ni<4;ni++){
      int r = col_off + ni*16 + loc;
      int slot = q ^ ((r>>1)&3);
      bfr[ni] = *(const bf16x8*)(Bs + r*32 + slot*8);
    }
    #pragma unroll
    for(int mi=0;mi<4;mi++)
      #pragma unroll
      for(int ni=0;ni<4;ni++)
        acc[mi][ni] = __builtin_amdgcn_mfma_f32_16x16x32_bf16(af[mi], bfr[ni], acc[mi][ni], 0,0,0);
    __syncthreads();
  }

  float* outFb = outF ? outF + (size_t)b*bO : nullptr;
  u16*   outBb = outB ? outB + (size_t)b*bO : nullptr;
  const float* nxb = nx ? nx + (size_t)b*NN : nullptr;
  const float* nyb = ny ? ny + (size_t)b*NN : nullptr;
  const float* Cb  = (MODE==MODE_STRUCT) ? Cs + (size_t)b*bO : nullptr;
  const float* mb  = (MODE==MODE_STRUCT) ? mu + (size_t)b*NN : nullptr;
  float lsum = 0.f;
  #pragma unroll
  for(int mi=0;mi<4;mi++){
    #pragma unroll
    for(int j=0;j<4;j++){
      int row = m0 + row_off + mi*16 + q*4 + j;
      float ir = 0.f, mr = 0.f;
      if(MODE==MODE_COST)   ir = 1.f/fmaxf(nxb[row],1e-12f);
      if(MODE==MODE_STRUCT) mr = mb[row];
      #pragma unroll
      for(int ni=0;ni<4;ni++){
        int col = n0 + col_off + ni*16 + loc;
        float v = acc[mi][ni][j];
        if(MODE==MODE_PROJ){
          v += bias[col];
          outBb[(size_t)row*ldo + col] = f2bf(v);
        } else if(MODE==MODE_COST){
          float ic = 1.f/fmaxf(nyb[col],1e-12f);
          v = 1.f - v*ir*ic;
          if(outFb) outFb[(size_t)row*ldo + col] = v;
          if(outBb) outBb[(size_t)row*ldo + col] = f2bf(v);
        } else if(MODE==MODE_PLAIN){
          outBb[(size_t)row*ldo + col] = f2bf(v);
        } else {
          float d = Cb[(size_t)row*ldo + col] - v;
          lsum += d*d*mr*mb[col];
        }
      }
    }
  }
  if(MODE==MODE_STRUCT){
    lsum = wred_sum(lsum);
    if(lane==0) red[w] = lsum;
    __syncthreads();
    if(tid==0) atomicAdd(accp+6, red[0]+red[1]+red[2]+red[3]);
  }
}

// ---------------- fused Sinkhorn: multiplicative domain, K in LDS ----------------
// one block (1024 thr) per (pass,batch). K = 2^(-C2*M) staged once into 128 KB
// dynamic LDS (chunk-rotation swizzle). 20 iterations of pure-FMA matvecs.
#define SINK_DYN_LDS 131072
__global__ __launch_bounds__(1024, 1) void k_sinkhorn_fused(
    const u16* __restrict__ Mbf, const float* __restrict__ muL,
    const float* __restrict__ nuL, u16* __restrict__ Gn, float* __restrict__ accp)
{
  extern __shared__ u16 Ks[];                      // 256x256 bf16, swizzled
  __shared__ __align__(16) float part[4096];       // reduction scratch
  __shared__ __align__(16) float su[NN], sv[NN], smu[NN], snu[NN];
  __shared__ float red[16];

  const int b = blockIdx.x;
  const int t = threadIdx.x;
  const u16* Mb = Mbf + (size_t)b*NN*NN;

  // stage K into LDS (coalesced global read, one-time exp2)
  #pragma unroll
  for(int i=0;i<16;i++){
    int e = (i*1024 + t)*4;
    int r = e>>8, c = e&255;
    ushort4 mv = *(const ushort4*)(Mb + e);
    ushort4 o;
    o.x = f2bf(exp2f(-C2LOG*bf2f(mv.x)));
    o.y = f2bf(exp2f(-C2LOG*bf2f(mv.y)));
    o.z = f2bf(exp2f(-C2LOG*bf2f(mv.z)));
    o.w = f2bf(exp2f(-C2LOG*bf2f(mv.w)));
    *(ushort4*)(Ks + LIDX(r,c)) = o;
  }
  if(t < NN){
    smu[t] = muL[(size_t)b*NN+t] + 1e-8f;
    snu[t] = nuL[(size_t)b*NN+t] + 1e-8f;
    sv[t] = 1.f;     // exp(v=0)
  }
  __syncthreads();

  const int r_ = t & 255, p_ = t >> 8;   // u-step: thread = (row, quarter)
  const int w = t>>6, l = t&63;          // v-step: wave-per-16-rows

  for(int it=0; it<20; it++){
    // ---- u-step: S_r = sum_c K[r][c]*v[c];  u_r = mu'_r / S_r ----
    {
      float sacc = 0.f;
      #pragma unroll
      for(int jj=0;jj<8;jj++){
        int c0 = p_*64 + jj*8;
        uint4 kv = *(const uint4*)(Ks + LIDX(r_, c0));
        float4 va = *(const float4*)(sv + c0);
        float4 vb = *(const float4*)(sv + c0 + 4);
        sacc += __uint_as_float(kv.x<<16)          * va.x;
        sacc += __uint_as_float(kv.x & 0xffff0000u)* va.y;
        sacc += __uint_as_float(kv.y<<16)          * va.z;
        sacc += __uint_as_float(kv.y & 0xffff0000u)* va.w;
        sacc += __uint_as_float(kv.z<<16)          * vb.x;
        sacc += __uint_as_float(kv.z & 0xffff0000u)* vb.y;
        sacc += __uint_as_float(kv.w<<16)          * vb.z;
        sacc += __uint_as_float(kv.w & 0xffff0000u)* vb.w;
      }
      part[t] = sacc;
    }
    __syncthreads();
    if(t < NN){
      float S = part[t] + part[256+t] + part[512+t] + part[768+t];
      su[t] = smu[t] / S;
    }
    __syncthreads();
    // ---- v-step: S_c = sum_r K[r][c]*u[r];  v_c = nu'_c / S_c ----
    {
      float cs0=0.f,cs1=0.f,cs2=0.f,cs3=0.f;
      #pragma unroll
      for(int rr=0;rr<16;rr++){
        int r = w*16 + rr;
        ushort4 kv = *(const ushort4*)(Ks + LIDX(r, l*4));
        float ur = su[r];
        cs0 = fmaf(bf2f(kv.x), ur, cs0);
        cs1 = fmaf(bf2f(kv.y), ur, cs1);
        cs2 = fmaf(bf2f(kv.z), ur, cs2);
        cs3 = fmaf(bf2f(kv.w), ur, cs3);
      }
      float4 o; o.x=cs0; o.y=cs1; o.z=cs2; o.w=cs3;
      *(float4*)(part + w*256 + l*4) = o;
    }
    __syncthreads();
    if(t < NN){
      float S = 0.f;
      #pragma unroll
      for(int ww=0;ww<16;ww++) S += part[ww*256 + t];
      sv[t] = snu[t] / S;
    }
    __syncthreads();
  }

  // rowsum pass: rowtot_r = u_r * (K v)_r + 1e-8  (stored as inverse in smu)
  {
    float sacc = 0.f;
    #pragma unroll
    for(int jj=0;jj<8;jj++){
      int c0 = p_*64 + jj*8;
      uint4 kv = *(const uint4*)(Ks + LIDX(r_, c0));
      float4 va = *(const float4*)(sv + c0);
      float4 vb = *(const float4*)(sv + c0 + 4);
      sacc += __uint_as_float(kv.x<<16)          * va.x;
      sacc += __uint_as_float(kv.x & 0xffff0000u)* va.y;
      sacc += __uint_as_float(kv.y<<16)          * va.z;
      sacc += __uint_as_float(kv.y & 0xffff0000u)* va.w;
      sacc += __uint_as_float(kv.z<<16)          * vb.x;
      sacc += __uint_as_float(kv.z & 0xffff0000u)* vb.y;
      sacc += __uint_as_float(kv.w<<16)          * vb.z;
      sacc += __uint_as_float(kv.w & 0xffff0000u)* vb.w;
    }
    part[t] = sacc;
  }
  __syncthreads();
  if(t < NN){
    float S = part[t] + part[256+t] + part[512+t] + part[768+t];
    smu[t] = 1.f / (su[t]*S + 1e-8f);
  }
  __syncthreads();

  // epilogue: Gamma = u*K*v; feat += M*Gamma (M = -log2(K)/C2); Gn = Gamma*inv
  u16* Gb = Gn + (size_t)b*NN*NN;
  const float IC = -1.f/C2LOG;
  float v0 = sv[l*4+0], v1 = sv[l*4+1], v2 = sv[l*4+2], v3 = sv[l*4+3];
  float fl = 0.f;
  for(int rr=0;rr<16;rr++){
    int r = w*16 + rr;
    ushort4 kv = *(const ushort4*)(Ks + LIDX(r, l*4));
    float k0=bf2f(kv.x), k1=bf2f(kv.y), k2=bf2f(kv.z), k3=bf2f(kv.w);
    float ur = su[r], inv = smu[r];
    float g0=ur*k0*v0, g1=ur*k1*v1, g2=ur*k2*v2, g3=ur*k3*v3;
    fl += g0*(__log2f(k0)*IC) + g1*(__log2f(k1)*IC)
        + g2*(__log2f(k2)*IC) + g3*(__log2f(k3)*IC);
    ushort4 o;
    o.x=f2bf(g0*inv); o.y=f2bf(g1*inv); o.z=f2bf(g2*inv); o.w=f2bf(g3*inv);
    *(ushort4*)(Gb + (size_t)r*NN + l*4) = o;
  }
  fl = wred_sum(fl);
  if(l==0) red[w] = fl;
  __syncthreads();
  if(t==0){
    float s=0.f;
    #pragma unroll
    for(int i=0;i<16;i++) s+=red[i];
    atomicAdd(accp+5, s);
  }
}

__global__ void k_final(const float* __restrict__ acc, float* __restrict__ out){
  out[0] = acc[0]
         + 20.f*acc[3]*(1.f/8128.f)
         + 40.f*acc[4]*(1.f/2048256.f)
         + 0.25f*(acc[5]+acc[6])*(1.f/64.f);
}

// ---------------- host ----------------
extern "C" void kernel_launch(void* const* d_in, const int* in_sizes, int n_in,
                              void* d_out, int out_size, void* d_ws, size_t ws_size,
                              hipStream_t stream) {
  const float* s_q_reps   = (const float*)d_in[0];
  const float* s_p_reps   = (const float*)d_in[1];
  const float* t_q_reps   = (const float*)d_in[2];
  const float* t_p_reps   = (const float*)d_in[3];
  const float* s_q_states = (const float*)d_in[4];
  const float* s_p_states = (const float*)d_in[5];
  const float* t_q_states = (const float*)d_in[6];
  const float* t_p_states = (const float*)d_in[7];
  const float* proj_w     = (const float*)d_in[8];
  const float* proj_b     = (const float*)d_in[9];
  float* ws = (float*)d_ws;
  float* acc = ws + OFF_ACC;
  u16* M_BF   = (u16*)(ws + OFF_MBF);
  u16* ZS_BF  = (u16*)(ws + OFF_ZS_BF);
  u16* ZT_BF  = (u16*)(ws + OFF_ZT_BF);
  u16* WT_BF  = (u16*)(ws + OFF_WT_BF);
  u16* ZSP_BF = (u16*)(ws + OFF_ZSP_BF);
  u16* GN_BF  = (u16*)(ws + OFF_GN_BF);
  u16* CT_BF  = (u16*)(ws + OFF_CT_BF);
  u16* T_BF   = (u16*)(ws + OFF_T_BF);

  // opt-in to >64KB dynamic LDS for the Sinkhorn kernel (idempotent)
  hipFuncSetAttribute(reinterpret_cast<const void*>(k_sinkhorn_fused),
                      hipFuncAttributeMaxDynamicSharedMemorySize, SINK_DYN_LDS);

  hipMemsetAsync(acc, 0, 16*sizeof(float), stream);

  // ---- Part A ----
  k_l2norm_rows<<<64,256,0,stream>>>(s_q_reps, ws+OFF_SQ128, 768, 128);
  k_l2norm_rows<<<64,256,0,stream>>>(s_p_reps, ws+OFF_SP128, 768, 128);
  k_l2norm_rows<<<64,256,0,stream>>>(t_q_reps, ws+OFF_TQ128, 768, 128);
  k_l2norm_rows<<<64,256,0,stream>>>(t_p_reps, ws+OFF_TP128, 768, 128);
  k_l2norm_rows<<<64,256,0,stream>>>(s_q_reps, ws+OFF_SQ768, 768, 768);
  k_l2norm_rows<<<64,256,0,stream>>>(s_p_reps, ws+OFF_SP768, 768, 768);
  k_contrastive<<<64,64,0,stream>>>(ws+OFF_SQ128, ws+OFF_SP128, 128, 1.0f, acc);
  k_contrastive<<<64,64,0,stream>>>(ws+OFF_SQ768, ws+OFF_SP768, 768, 2.0f, acc);
  k_gram_ds<<<128,128,0,stream>>>(ws+OFF_SQ128, ws+OFF_TQ128, ws+OFF_DS, ws+OFF_DT, acc);
  k_rkd_dist<<<128,128,0,stream>>>(ws+OFF_DS, ws+OFF_DT, acc);
  k_rkd_angle<<<128,256,65532,stream>>>(ws+OFF_SQ128, ws+OFF_TQ128, ws+OFF_PSI, acc);

  k_wt<<<dim3(HTT/32, HSS/32),dim3(32,8),0,stream>>>(proj_w, WT_BF);

  // ---- Part B phase 1: per-pass GEMMs into doubled buffers ----
  for(int pass=0; pass<2; pass++){
    const float* zs = pass ? s_p_states : s_q_states;
    const float* zt = pass ? t_p_states : t_q_states;
    size_t po  = (size_t)pass*NB*NN*NN;   // per-pass matrix offset
    size_t pr  = (size_t)pass*ROWS;       // per-pass row-vector offset
    k_cvt_norm<<<ROWS,256,0,stream>>>(zs, ZS_BF, ws+OFF_NS, HSS);
    k_cvt_norm<<<ROWS,256,0,stream>>>(zt, ZT_BF, ws+OFF_NT, HTT);
    k_saliency<<<NB,256,0,stream>>>(ws+OFF_NS, ws+OFF_MU+pr);
    k_saliency<<<NB,256,0,stream>>>(ws+OFF_NT, ws+OFF_NU+pr);
    k_mfma<MODE_PROJ><<<dim3(HTT/128, ROWS/128, 1),256,0,stream>>>(
        ZS_BF, HSS, 0, WT_BF, HSS, 0, HSS,
        nullptr, ZSP_BF, HTT, 0,
        nullptr, nullptr, proj_b, nullptr, nullptr, nullptr);
    k_row_norm_bf16<<<ROWS,256,0,stream>>>(ZSP_BF, ws+OFF_NSP, HTT);
    // C_s (f32)
    k_mfma<MODE_COST><<<dim3(2,2,NB),256,0,stream>>>(
        ZS_BF, HSS, (long)NN*HSS, ZS_BF, HSS, (long)NN*HSS, HSS,
        ws+OFF_CS+po, nullptr, NN, (long)NN*NN,
        ws+OFF_NS, ws+OFF_NS, nullptr, nullptr, nullptr, nullptr);
    // C_t (bf16)
    k_mfma<MODE_COST><<<dim3(2,2,NB),256,0,stream>>>(
        ZT_BF, HTT, (long)NN*HTT, ZT_BF, HTT, (long)NN*HTT, HTT,
        nullptr, CT_BF+po, NN, (long)NN*NN,
        ws+OFF_NT, ws+OFF_NT, nullptr, nullptr, nullptr, nullptr);
    // M (bf16)
    k_mfma<MODE_COST><<<dim3(2,2,NB),256,0,stream>>>(
        ZSP_BF, HTT, (long)NN*HTT, ZT_BF, HTT, (long)NN*HTT, HTT,
        nullptr, M_BF+po, NN, (long)NN*NN,
        ws+OFF_NSP, ws+OFF_NT, nullptr, nullptr, nullptr, nullptr);
  }

  // ---- Part B phase 2: Sinkhorn (both passes, multiplicative, K in LDS) ----
  k_sinkhorn_fused<<<2*NB,1024,SINK_DYN_LDS,stream>>>(
      M_BF, ws+OFF_MU, ws+OFF_NU, GN_BF, acc);

  // ---- Part B phase 3: T = Gn@Ct, struct loss (batched over both passes) ----
  k_mfma<MODE_PLAIN><<<dim3(2,2,2*NB),256,0,stream>>>(
      GN_BF, NN, (long)NN*NN, CT_BF, NN, (long)NN*NN, NN,
      nullptr, T_BF, NN, (long)NN*NN,
      nullptr, nullptr, nullptr, nullptr, nullptr, nullptr);
  k_mfma<MODE_STRUCT><<<dim3(2,2,2*NB),256,0,stream>>>(
      T_BF, NN, (long)NN*NN, GN_BF, NN, (long)NN*NN, NN,
      nullptr, nullptr, NN, (long)NN*NN,
      nullptr, nullptr, nullptr, ws+OFF_CS, ws+OFF_MU, acc);

  k_final<<<1,1,0,stream>>>(acc, (float*)d_out);
}

// Round 6
// 860.633 us; speedup vs baseline: 3.4157x; 1.1452x over previous
//
#include <hip/hip_runtime.h>
#include <math.h>

// Problem dims
#define NB   64      // batch B
#define NN   256     // tokens N
#define HSS  768     // H_S
#define HTT  1024    // H_T
#define ROWS (NB*NN) // 16384
#define C2LOG 14.426950408889634f  // 10 * log2(e)

typedef unsigned short u16;
typedef __attribute__((ext_vector_type(8))) short bf16x8;
typedef __attribute__((ext_vector_type(4))) float f32x4;

// swizzled LDS index for K[r][c] (256 cols): chunk rotation, 8-u16 granularity
#define LIDX(r,c) (((r)<<8) + (((((c)>>3) + (r)) & 31)<<3) + ((c)&7))
// swizzled LDS index for E[r][c] (128 cols, 16 chunks of 8)
#define EIDX(r,c) (((r)<<7) + (((((c)>>3) + (r)) & 15)<<3) + ((c)&7))

// ---------------- workspace layout (float offsets) ----------------
static const size_t OFF_ACC   = 0;                          // 16 floats
static const size_t OFF_SQ128 = 16;
static const size_t OFF_SP128 = OFF_SQ128 + 64*128;
static const size_t OFF_TQ128 = OFF_SP128 + 64*128;
static const size_t OFF_TP128 = OFF_TQ128 + 64*128;
static const size_t OFF_SQ768 = OFF_TP128 + 64*128;
static const size_t OFF_SP768 = OFF_SQ768 + 64*768;
static const size_t OFF_DS    = OFF_SP768 + 64*768;         // 128*128
static const size_t OFF_DT    = OFF_DS + 128*128;
static const size_t OFF_CS    = OFF_DT + 128*128;           // 2*B*N*N f32
static const size_t OFF_MBF   = OFF_CS  + (size_t)2*NB*NN*NN;     // 2*B*N*N bf16
static const size_t OFF_ZS_BF = OFF_MBF + (size_t)NB*NN*NN;       // 16384x768 bf16
static const size_t OFF_ZT_BF = OFF_ZS_BF + (size_t)ROWS*HSS/2;   // 16384x1024 bf16
static const size_t OFF_WT_BF = OFF_ZT_BF + (size_t)ROWS*HTT/2;   // 1024x768 bf16
static const size_t OFF_ZSP_BF= OFF_WT_BF + (size_t)HTT*HSS/2;    // 16384x1024 bf16
static const size_t OFF_GN_BF = OFF_ZSP_BF+ (size_t)ROWS*HTT/2;   // 2*B*N*N bf16
static const size_t OFF_CT_BF = OFF_GN_BF + (size_t)NB*NN*NN;     // 2*B*N*N bf16
static const size_t OFF_T_BF  = OFF_ZS_BF;                  // ALIAS: ZS dead after cost GEMMs
static const size_t OFF_NS    = OFF_CT_BF + (size_t)NB*NN*NN;
static const size_t OFF_NT    = OFF_NS + ROWS;
static const size_t OFF_NSP   = OFF_NT + ROWS;
static const size_t OFF_MU    = OFF_NSP + ROWS;             // 2*ROWS (linear)
static const size_t OFF_NU    = OFF_MU + 2*ROWS;            // 2*ROWS (linear)

// acc: 0=contrastive 1=ds_sum 2=dt_sum 3=dist_huber 4=angle_huber 5=feat 6=struct

// ---------------- helpers ----------------
__device__ __forceinline__ float wred_sum(float v){
  #pragma unroll
  for(int o=32;o>0;o>>=1) v += __shfl_xor(v,o,64);
  return v;
}
__device__ __forceinline__ float wred_max(float v){
  #pragma unroll
  for(int o=32;o>0;o>>=1) v = fmaxf(v, __shfl_xor(v,o,64));
  return v;
}
__device__ __forceinline__ u16 f2bf(float f){
  unsigned u = __float_as_uint(f);
  unsigned r = (u + 0x7fffu + ((u>>16)&1u)) >> 16;
  return (u16)r;
}
__device__ __forceinline__ float bf2f(u16 h){
  return __uint_as_float(((unsigned)h)<<16);
}

// ---------------- Part A kernels ----------------
__global__ __launch_bounds__(256) void k_l2norm_rows(const float* __restrict__ in,
    float* __restrict__ out, int k_in, int k_use){
  int r = blockIdx.x;
  const float* row = in + (size_t)r*k_in;
  float ss = 0.f;
  for(int d=threadIdx.x; d<k_use; d+=256){ float x=row[d]; ss += x*x; }
  ss = wred_sum(ss);
  __shared__ float sm[4];
  if((threadIdx.x&63)==0) sm[threadIdx.x>>6]=ss;
  __syncthreads();
  float tot = sm[0]+sm[1]+sm[2]+sm[3];
  float inv = 1.f / fmaxf(sqrtf(tot), 1e-12f);
  for(int d=threadIdx.x; d<k_use; d+=256) out[(size_t)r*k_use + d] = row[d]*inv;
}

__global__ __launch_bounds__(64) void k_contrastive(const float* __restrict__ q,
    const float* __restrict__ p, int dim, float weight, float* __restrict__ acc){
  int i = blockIdx.x, j = threadIdx.x;
  const float* qi = q + (size_t)i*dim;
  const float* pj = p + (size_t)j*dim;
  float dot = 0.f;
  for(int d=0; d<dim; d++) dot += qi[d]*pj[d];
  float s = dot / 0.07f;
  float mx = wred_max(s);
  float e = expf(s - mx);
  float Z = wred_sum(e);
  float logZ = mx + logf(Z);
  float diag = __shfl(s, i, 64);
  if(j==0) atomicAdd(acc+0, weight*(logZ - diag)*(1.f/64.f));
}

__global__ __launch_bounds__(128) void k_gram_ds(const float* __restrict__ sb,
    const float* __restrict__ tb, float* __restrict__ ds, float* __restrict__ dt,
    float* __restrict__ acc){
  int r = blockIdx.x, c = threadIdx.x;
  const float* sr = sb + r*128; const float* sc = sb + c*128;
  const float* tr = tb + r*128; const float* tc = tb + c*128;
  float dot_s=0,ssr=0,ssc=0,dot_t=0,tsr=0,tsc=0;
  for(int d=0; d<128; d++){
    float a=sr[d], b=sc[d]; dot_s += a*b; ssr += a*a; ssc += b*b;
    float at=tr[d], bt=tc[d]; dot_t += at*bt; tsr += at*at; tsc += bt*bt;
  }
  float dv = ssr + ssc - 2.f*dot_s;
  float tv = tsr + tsc - 2.f*dot_t;
  ds[r*128+c] = dv; dt[r*128+c] = tv;
  float ms = (c>r)? dv : 0.f;
  float mt = (c>r)? tv : 0.f;
  ms = wred_sum(ms); mt = wred_sum(mt);
  __shared__ float sm[2][2];
  if((threadIdx.x&63)==0){ sm[0][threadIdx.x>>6]=ms; sm[1][threadIdx.x>>6]=mt; }
  __syncthreads();
  if(threadIdx.x==0){ atomicAdd(acc+1, sm[0][0]+sm[0][1]); atomicAdd(acc+2, sm[1][0]+sm[1][1]); }
}

__global__ __launch_bounds__(128) void k_rkd_dist(const float* __restrict__ ds,
    const float* __restrict__ dt, float* __restrict__ acc){
  int r=blockIdx.x, c=threadIdx.x;
  float mean_s = acc[1]*(1.f/8128.f) + 1e-8f;
  float mean_t = acc[2]*(1.f/8128.f) + 1e-8f;
  float h=0.f;
  if(c>r){
    float diff = ds[r*128+c]/mean_s - dt[r*128+c]/mean_t;
    float a = fabsf(diff);
    h = (a<1.f)? 0.5f*a*a : a-0.5f;
  }
  h = wred_sum(h);
  __shared__ float sm[2];
  if((threadIdx.x&63)==0) sm[threadIdx.x>>6]=h;
  __syncthreads();
  if(threadIdx.x==0) atomicAdd(acc+3, sm[0]+sm[1]);
}

// ---- RKD angle via MFMA: psi = E E^T, E in bf16 LDS, huber fused ----
// grid (j, colhalf) = 256 blocks x 256 thr. 64KB dynamic LDS: Es,Et (128x128 bf16).
#define RKD_LDS 65536
__global__ __launch_bounds__(256, 1) void k_rkd_angle_mfma(
    const float* __restrict__ sb, const float* __restrict__ tb,
    float* __restrict__ accp)
{
  extern __shared__ u16 eSh[];
  u16* Es = eSh;
  u16* Et = eSh + 128*128;
  const int j    = blockIdx.x >> 1;
  const int half = blockIdx.x & 1;
  const int tid = threadIdx.x;
  // stage e-vectors: 2 threads per row (i = tid/2, h = tid&1 -> 64 elems)
  {
    const int i = tid >> 1, h = tid & 1;
    #pragma unroll
    for(int which=0; which<2; which++){
      const float* xb = which ? tb : sb;
      u16* E = which ? Et : Es;
      const float* xj = xb + j*128 + h*64;
      const float* xi = xb + i*128 + h*64;
      float ss = 0.f;
      #pragma unroll
      for(int d4=0; d4<16; d4++){
        float4 a = *(const float4*)(xj + d4*4);
        float4 b = *(const float4*)(xi + d4*4);
        float d0=a.x-b.x, d1=a.y-b.y, d2=a.z-b.z, d3=a.w-b.w;
        ss += d0*d0+d1*d1+d2*d2+d3*d3;
      }
      ss += __shfl_xor(ss, 1, 64);
      float inv = (i==j) ? 0.f : 1.f/(sqrtf(ss)+1e-8f);
      #pragma unroll
      for(int d4=0; d4<16; d4++){
        float4 a = *(const float4*)(xj + d4*4);
        float4 b = *(const float4*)(xi + d4*4);
        int c = h*64 + d4*4;
        E[EIDX(i,c+0)] = f2bf((a.x-b.x)*inv);
        E[EIDX(i,c+1)] = f2bf((a.y-b.y)*inv);
        E[EIDX(i,c+2)] = f2bf((a.z-b.z)*inv);
        E[EIDX(i,c+3)] = f2bf((a.w-b.w)*inv);
      }
    }
  }
  __syncthreads();
  // MFMA: wave w computes rows [w*32,w*32+32) x cols [half*64, half*64+64)
  const int w = tid >> 6, lane = tid & 63;
  const int q = lane >> 4, loc = lane & 15;
  float hsum = 0.f;
  #pragma unroll
  for(int ni=0; ni<4; ni++){
    const int cb = half*64 + ni*16;
    #pragma unroll
    for(int mi=0; mi<2; mi++){
      const int rb = w*32 + mi*16;
      f32x4 as_ = {0.f,0.f,0.f,0.f}, at_ = {0.f,0.f,0.f,0.f};
      #pragma unroll
      for(int k0=0; k0<128; k0+=32){
        int ra = rb + loc, rbn = cb + loc;
        int ca = k0 + q*8;
        bf16x8 aS = *(const bf16x8*)(Es + EIDX(ra, ca));
        bf16x8 bS = *(const bf16x8*)(Es + EIDX(rbn, ca));
        bf16x8 aT = *(const bf16x8*)(Et + EIDX(ra, ca));
        bf16x8 bT = *(const bf16x8*)(Et + EIDX(rbn, ca));
        as_ = __builtin_amdgcn_mfma_f32_16x16x32_bf16(aS, bS, as_, 0,0,0);
        at_ = __builtin_amdgcn_mfma_f32_16x16x32_bf16(aT, bT, at_, 0,0,0);
      }
      // huber on diff; D[row][col]: row = rb + q*4 + jj, col = cb + loc
      #pragma unroll
      for(int jj=0; jj<4; jj++){
        int row = rb + q*4 + jj, col = cb + loc;
        if(row != col){
          float d = as_[jj] - at_[jj];
          float a = fabsf(d);
          hsum += (a < 1.f) ? 0.5f*a*a : a - 0.5f;
        }
      }
    }
  }
  hsum = wred_sum(hsum);
  __syncthreads();               // eSh reads done; reuse as scratch
  float* red = (float*)eSh;
  if(lane==0) red[w] = hsum;
  __syncthreads();
  if(tid==0) atomicAdd(accp+4, red[0]+red[1]+red[2]+red[3]);
}

// ---------------- Part B: convert+norm / saliency ----------------
__global__ __launch_bounds__(256) void k_cvt_norm(const float* __restrict__ in,
    u16* __restrict__ out, float* __restrict__ nrm, int K){
  int r = blockIdx.x;
  const float* row = in + (size_t)r*K;
  u16* orow = out + (size_t)r*K;
  float ss=0.f;
  for(int d=threadIdx.x; d<K; d+=256){ float x=row[d]; ss+=x*x; orow[d]=f2bf(x); }
  ss = wred_sum(ss);
  __shared__ float sm[4];
  if((threadIdx.x&63)==0) sm[threadIdx.x>>6]=ss;
  __syncthreads();
  if(threadIdx.x==0) nrm[r] = sqrtf(sm[0]+sm[1]+sm[2]+sm[3]);
}

__global__ __launch_bounds__(256) void k_row_norm_bf16(const u16* __restrict__ z,
    float* __restrict__ nrm, int K){
  int r = blockIdx.x;
  const u16* row = z + (size_t)r*K;
  float ss=0.f;
  for(int d=threadIdx.x; d<K; d+=256){ float x=bf2f(row[d]); ss+=x*x; }
  ss = wred_sum(ss);
  __shared__ float sm[4];
  if((threadIdx.x&63)==0) sm[threadIdx.x>>6]=ss;
  __syncthreads();
  if(threadIdx.x==0) nrm[r] = sqrtf(sm[0]+sm[1]+sm[2]+sm[3]);
}

// W (HSS x HTT) f32 -> Wt (HTT x HSS) bf16
__global__ void k_wt(const float* __restrict__ W, u16* __restrict__ Wt){
  __shared__ float t[32][33];
  int k0 = blockIdx.y*32, n0 = blockIdx.x*32;
  int tx = threadIdx.x, ty = threadIdx.y;
  for(int r=0;r<32;r+=8) t[ty+r][tx] = W[(size_t)(k0+ty+r)*HTT + n0+tx];
  __syncthreads();
  for(int r=0;r<32;r+=8) Wt[(size_t)(n0+ty+r)*HSS + k0+tx] = f2bf(t[tx][ty+r]);
}

// softmax over N (linear output)
__global__ __launch_bounds__(256) void k_saliency(const float* __restrict__ nrm,
    float* __restrict__ out){
  int b = blockIdx.x, n = threadIdx.x;
  float x = nrm[b*NN+n];
  float mx = wred_max(x);
  __shared__ float sm[4], sm2[4];
  if((n&63)==0) sm[n>>6]=mx;
  __syncthreads();
  mx = fmaxf(fmaxf(sm[0],sm[1]),fmaxf(sm[2],sm[3]));
  float e = expf(x-mx);
  float s = wred_sum(e);
  if((n&63)==0) sm2[n>>6]=s;
  __syncthreads();
  s = sm2[0]+sm2[1]+sm2[2]+sm2[3];
  out[b*NN+n] = e/s;
}

// ---------------- MFMA GEMM (NT form) ----------------
enum { MODE_PROJ=0, MODE_COST=1, MODE_PLAIN=2, MODE_STRUCT=3 };

template<int MODE>
__global__ __launch_bounds__(256) void k_mfma(
    const u16* __restrict__ A, int lda, long bA,
    const u16* __restrict__ B, int ldb, long bB,
    int K,
    float* __restrict__ outF, u16* __restrict__ outB, int ldo, long bO,
    const float* __restrict__ nx, const float* __restrict__ ny,
    const float* __restrict__ bias,
    const float* __restrict__ Cs, const float* __restrict__ mu,
    float* __restrict__ accp)
{
  __shared__ u16 As[128*32];
  __shared__ u16 Bs[128*32];
  __shared__ float red[4];
  int b = blockIdx.z;
  const u16* Ab = A + (size_t)b*bA;
  const u16* Bb = B + (size_t)b*bB;
  int tid = threadIdx.x;
  int lane = tid & 63, w = tid >> 6;
  int m0 = blockIdx.y*128, n0 = blockIdx.x*128;
  int row_off = (w>>1)*64, col_off = (w&1)*64;
  int q = lane>>4, loc = lane&15;
  f32x4 acc[4][4] = {};
  int srow = tid >> 2;
  int skc  = tid & 3;

  for(int k0=0;k0<K;k0+=32){
    #pragma unroll
    for(int h=0;h<2;h++){
      int row = srow + h*64;
      int slot = skc ^ ((row>>1)&3);
      uint4 av = *(const uint4*)(Ab + (size_t)(m0+row)*lda + k0 + skc*8);
      uint4 bv = *(const uint4*)(Bb + (size_t)(n0+row)*ldb + k0 + skc*8);
      *(uint4*)(As + row*32 + slot*8) = av;
      *(uint4*)(Bs + row*32 + slot*8) = bv;
    }
    __syncthreads();
    bf16x8 af[4], bfr[4];
    #pragma unroll
    for(int mi=0;mi<4;mi++){
      int r = row_off + mi*16 + loc;
      int slot = q ^ ((r>>1)&3);
      af[mi] = *(const bf16x8*)(As + r*32 + slot*8);
    }
    #pragma unroll
    for(int ni=0;ni<4;ni++){
      int r = col_off + ni*16 + loc;
      int slot = q ^ ((r>>1)&3);
      bfr[ni] = *(const bf16x8*)(Bs + r*32 + slot*8);
    }
    #pragma unroll
    for(int mi=0;mi<4;mi++)
      #pragma unroll
      for(int ni=0;ni<4;ni++)
        acc[mi][ni] = __builtin_amdgcn_mfma_f32_16x16x32_bf16(af[mi], bfr[ni], acc[mi][ni], 0,0,0);
    __syncthreads();
  }

  float* outFb = outF ? outF + (size_t)b*bO : nullptr;
  u16*   outBb = outB ? outB + (size_t)b*bO : nullptr;
  const float* nxb = nx ? nx + (size_t)b*NN : nullptr;
  const float* nyb = ny ? ny + (size_t)b*NN : nullptr;
  const float* Cb  = (MODE==MODE_STRUCT) ? Cs + (size_t)b*bO : nullptr;
  const float* mb  = (MODE==MODE_STRUCT) ? mu + (size_t)b*NN : nullptr;
  float lsum = 0.f;
  #pragma unroll
  for(int mi=0;mi<4;mi++){
    #pragma unroll
    for(int j=0;j<4;j++){
      int row = m0 + row_off + mi*16 + q*4 + j;
      float ir = 0.f, mr = 0.f;
      if(MODE==MODE_COST)   ir = 1.f/fmaxf(nxb[row],1e-12f);
      if(MODE==MODE_STRUCT) mr = mb[row];
      #pragma unroll
      for(int ni=0;ni<4;ni++){
        int col = n0 + col_off + ni*16 + loc;
        float v = acc[mi][ni][j];
        if(MODE==MODE_PROJ){
          v += bias[col];
          outBb[(size_t)row*ldo + col] = f2bf(v);
        } else if(MODE==MODE_COST){
          float ic = 1.f/fmaxf(nyb[col],1e-12f);
          v = 1.f - v*ir*ic;
          if(outFb) outFb[(size_t)row*ldo + col] = v;
          if(outBb) outBb[(size_t)row*ldo + col] = f2bf(v);
        } else if(MODE==MODE_PLAIN){
          outBb[(size_t)row*ldo + col] = f2bf(v);
        } else {
          float d = Cb[(size_t)row*ldo + col] - v;
          lsum += d*d*mr*mb[col];
        }
      }
    }
  }
  if(MODE==MODE_STRUCT){
    lsum = wred_sum(lsum);
    if(lane==0) red[w] = lsum;
    __syncthreads();
    if(tid==0) atomicAdd(accp+6, red[0]+red[1]+red[2]+red[3]);
  }
}

// ---------------- fused Sinkhorn: multiplicative domain, K in LDS ----------------
#define SINK_DYN_LDS 131072
__global__ __launch_bounds__(1024, 1) void k_sinkhorn_fused(
    const u16* __restrict__ Mbf, const float* __restrict__ muL,
    const float* __restrict__ nuL, u16* __restrict__ Gn, float* __restrict__ accp)
{
  extern __shared__ u16 Ks[];                      // 256x256 bf16, swizzled
  __shared__ __align__(16) float part[4096];       // reduction scratch
  __shared__ __align__(16) float su[NN], sv[NN], smu[NN], snu[NN];
  __shared__ float red[16];

  const int b = blockIdx.x;
  const int t = threadIdx.x;
  const u16* Mb = Mbf + (size_t)b*NN*NN;

  #pragma unroll
  for(int i=0;i<16;i++){
    int e = (i*1024 + t)*4;
    int r = e>>8, c = e&255;
    ushort4 mv = *(const ushort4*)(Mb + e);
    ushort4 o;
    o.x = f2bf(exp2f(-C2LOG*bf2f(mv.x)));
    o.y = f2bf(exp2f(-C2LOG*bf2f(mv.y)));
    o.z = f2bf(exp2f(-C2LOG*bf2f(mv.z)));
    o.w = f2bf(exp2f(-C2LOG*bf2f(mv.w)));
    *(ushort4*)(Ks + LIDX(r,c)) = o;
  }
  if(t < NN){
    smu[t] = muL[(size_t)b*NN+t] + 1e-8f;
    snu[t] = nuL[(size_t)b*NN+t] + 1e-8f;
    sv[t] = 1.f;
  }
  __syncthreads();

  const int r_ = t & 255, p_ = t >> 8;
  const int w = t>>6, l = t&63;

  for(int it=0; it<20; it++){
    {
      float sacc = 0.f;
      #pragma unroll
      for(int jj=0;jj<8;jj++){
        int c0 = p_*64 + jj*8;
        uint4 kv = *(const uint4*)(Ks + LIDX(r_, c0));
        float4 va = *(const float4*)(sv + c0);
        float4 vb = *(const float4*)(sv + c0 + 4);
        sacc += __uint_as_float(kv.x<<16)          * va.x;
        sacc += __uint_as_float(kv.x & 0xffff0000u)* va.y;
        sacc += __uint_as_float(kv.y<<16)          * va.z;
        sacc += __uint_as_float(kv.y & 0xffff0000u)* va.w;
        sacc += __uint_as_float(kv.z<<16)          * vb.x;
        sacc += __uint_as_float(kv.z & 0xffff0000u)* vb.y;
        sacc += __uint_as_float(kv.w<<16)          * vb.z;
        sacc += __uint_as_float(kv.w & 0xffff0000u)* vb.w;
      }
      part[t] = sacc;
    }
    __syncthreads();
    if(t < NN){
      float S = part[t] + part[256+t] + part[512+t] + part[768+t];
      su[t] = smu[t] / S;
    }
    __syncthreads();
    {
      float cs0=0.f,cs1=0.f,cs2=0.f,cs3=0.f;
      #pragma unroll
      for(int rr=0;rr<16;rr++){
        int r = w*16 + rr;
        ushort4 kv = *(const ushort4*)(Ks + LIDX(r, l*4));
        float ur = su[r];
        cs0 = fmaf(bf2f(kv.x), ur, cs0);
        cs1 = fmaf(bf2f(kv.y), ur, cs1);
        cs2 = fmaf(bf2f(kv.z), ur, cs2);
        cs3 = fmaf(bf2f(kv.w), ur, cs3);
      }
      float4 o; o.x=cs0; o.y=cs1; o.z=cs2; o.w=cs3;
      *(float4*)(part + w*256 + l*4) = o;
    }
    __syncthreads();
    if(t < NN){
      float S = 0.f;
      #pragma unroll
      for(int ww=0;ww<16;ww++) S += part[ww*256 + t];
      sv[t] = snu[t] / S;
    }
    __syncthreads();
  }

  {
    float sacc = 0.f;
    #pragma unroll
    for(int jj=0;jj<8;jj++){
      int c0 = p_*64 + jj*8;
      uint4 kv = *(const uint4*)(Ks + LIDX(r_, c0));
      float4 va = *(const float4*)(sv + c0);
      float4 vb = *(const float4*)(sv + c0 + 4);
      sacc += __uint_as_float(kv.x<<16)          * va.x;
      sacc += __uint_as_float(kv.x & 0xffff0000u)* va.y;
      sacc += __uint_as_float(kv.y<<16)          * va.z;
      sacc += __uint_as_float(kv.y & 0xffff0000u)* va.w;
      sacc += __uint_as_float(kv.z<<16)          * vb.x;
      sacc += __uint_as_float(kv.z & 0xffff0000u)* vb.y;
      sacc += __uint_as_float(kv.w<<16)          * vb.z;
      sacc += __uint_as_float(kv.w & 0xffff0000u)* vb.w;
    }
    part[t] = sacc;
  }
  __syncthreads();
  if(t < NN){
    float S = part[t] + part[256+t] + part[512+t] + part[768+t];
    smu[t] = 1.f / (su[t]*S + 1e-8f);
  }
  __syncthreads();

  u16* Gb = Gn + (size_t)b*NN*NN;
  const float IC = -1.f/C2LOG;
  float v0 = sv[l*4+0], v1 = sv[l*4+1], v2 = sv[l*4+2], v3 = sv[l*4+3];
  float fl = 0.f;
  for(int rr=0;rr<16;rr++){
    int r = w*16 + rr;
    ushort4 kv = *(const ushort4*)(Ks + LIDX(r, l*4));
    float k0=bf2f(kv.x), k1=bf2f(kv.y), k2=bf2f(kv.z), k3=bf2f(kv.w);
    float ur = su[r], inv = smu[r];
    float g0=ur*k0*v0, g1=ur*k1*v1, g2=ur*k2*v2, g3=ur*k3*v3;
    fl += g0*(__log2f(k0)*IC) + g1*(__log2f(k1)*IC)
        + g2*(__log2f(k2)*IC) + g3*(__log2f(k3)*IC);
    ushort4 o;
    o.x=f2bf(g0*inv); o.y=f2bf(g1*inv); o.z=f2bf(g2*inv); o.w=f2bf(g3*inv);
    *(ushort4*)(Gb + (size_t)r*NN + l*4) = o;
  }
  fl = wred_sum(fl);
  if(l==0) red[w] = fl;
  __syncthreads();
  if(t==0){
    float s=0.f;
    #pragma unroll
    for(int i=0;i<16;i++) s+=red[i];
    atomicAdd(accp+5, s);
  }
}

__global__ void k_final(const float* __restrict__ acc, float* __restrict__ out){
  out[0] = acc[0]
         + 20.f*acc[3]*(1.f/8128.f)
         + 40.f*acc[4]*(1.f/2048256.f)
         + 0.25f*(acc[5]+acc[6])*(1.f/64.f);
}

// ---------------- host ----------------
extern "C" void kernel_launch(void* const* d_in, const int* in_sizes, int n_in,
                              void* d_out, int out_size, void* d_ws, size_t ws_size,
                              hipStream_t stream) {
  const float* s_q_reps   = (const float*)d_in[0];
  const float* s_p_reps   = (const float*)d_in[1];
  const float* t_q_reps   = (const float*)d_in[2];
  const float* t_p_reps   = (const float*)d_in[3];
  const float* s_q_states = (const float*)d_in[4];
  const float* s_p_states = (const float*)d_in[5];
  const float* t_q_states = (const float*)d_in[6];
  const float* t_p_states = (const float*)d_in[7];
  const float* proj_w     = (const float*)d_in[8];
  const float* proj_b     = (const float*)d_in[9];
  float* ws = (float*)d_ws;
  float* acc = ws + OFF_ACC;
  u16* M_BF   = (u16*)(ws + OFF_MBF);
  u16* ZS_BF  = (u16*)(ws + OFF_ZS_BF);
  u16* ZT_BF  = (u16*)(ws + OFF_ZT_BF);
  u16* WT_BF  = (u16*)(ws + OFF_WT_BF);
  u16* ZSP_BF = (u16*)(ws + OFF_ZSP_BF);
  u16* GN_BF  = (u16*)(ws + OFF_GN_BF);
  u16* CT_BF  = (u16*)(ws + OFF_CT_BF);
  u16* T_BF   = (u16*)(ws + OFF_T_BF);

  hipFuncSetAttribute(reinterpret_cast<const void*>(k_sinkhorn_fused),
                      hipFuncAttributeMaxDynamicSharedMemorySize, SINK_DYN_LDS);
  hipFuncSetAttribute(reinterpret_cast<const void*>(k_rkd_angle_mfma),
                      hipFuncAttributeMaxDynamicSharedMemorySize, RKD_LDS);

  hipMemsetAsync(acc, 0, 16*sizeof(float), stream);

  // ---- Part A ----
  k_l2norm_rows<<<64,256,0,stream>>>(s_q_reps, ws+OFF_SQ128, 768, 128);
  k_l2norm_rows<<<64,256,0,stream>>>(s_p_reps, ws+OFF_SP128, 768, 128);
  k_l2norm_rows<<<64,256,0,stream>>>(t_q_reps, ws+OFF_TQ128, 768, 128);
  k_l2norm_rows<<<64,256,0,stream>>>(t_p_reps, ws+OFF_TP128, 768, 128);
  k_l2norm_rows<<<64,256,0,stream>>>(s_q_reps, ws+OFF_SQ768, 768, 768);
  k_l2norm_rows<<<64,256,0,stream>>>(s_p_reps, ws+OFF_SP768, 768, 768);
  k_contrastive<<<64,64,0,stream>>>(ws+OFF_SQ128, ws+OFF_SP128, 128, 1.0f, acc);
  k_contrastive<<<64,64,0,stream>>>(ws+OFF_SQ768, ws+OFF_SP768, 768, 2.0f, acc);
  k_gram_ds<<<128,128,0,stream>>>(ws+OFF_SQ128, ws+OFF_TQ128, ws+OFF_DS, ws+OFF_DT, acc);
  k_rkd_dist<<<128,128,0,stream>>>(ws+OFF_DS, ws+OFF_DT, acc);
  k_rkd_angle_mfma<<<256,256,RKD_LDS,stream>>>(ws+OFF_SQ128, ws+OFF_TQ128, acc);

  k_wt<<<dim3(HTT/32, HSS/32),dim3(32,8),0,stream>>>(proj_w, WT_BF);

  // ---- Part B phase 1: per-pass GEMMs into doubled buffers ----
  for(int pass=0; pass<2; pass++){
    const float* zs = pass ? s_p_states : s_q_states;
    const float* zt = pass ? t_p_states : t_q_states;
    size_t po  = (size_t)pass*NB*NN*NN;
    size_t pr  = (size_t)pass*ROWS;
    k_cvt_norm<<<ROWS,256,0,stream>>>(zs, ZS_BF, ws+OFF_NS, HSS);
    k_cvt_norm<<<ROWS,256,0,stream>>>(zt, ZT_BF, ws+OFF_NT, HTT);
    k_saliency<<<NB,256,0,stream>>>(ws+OFF_NS, ws+OFF_MU+pr);
    k_saliency<<<NB,256,0,stream>>>(ws+OFF_NT, ws+OFF_NU+pr);
    k_mfma<MODE_PROJ><<<dim3(HTT/128, ROWS/128, 1),256,0,stream>>>(
        ZS_BF, HSS, 0, WT_BF, HSS, 0, HSS,
        nullptr, ZSP_BF, HTT, 0,
        nullptr, nullptr, proj_b, nullptr, nullptr, nullptr);
    k_row_norm_bf16<<<ROWS,256,0,stream>>>(ZSP_BF, ws+OFF_NSP, HTT);
    // C_s (f32)
    k_mfma<MODE_COST><<<dim3(2,2,NB),256,0,stream>>>(
        ZS_BF, HSS, (long)NN*HSS, ZS_BF, HSS, (long)NN*HSS, HSS,
        ws+OFF_CS+po, nullptr, NN, (long)NN*NN,
        ws+OFF_NS, ws+OFF_NS, nullptr, nullptr, nullptr, nullptr);
    // C_t (bf16)
    k_mfma<MODE_COST><<<dim3(2,2,NB),256,0,stream>>>(
        ZT_BF, HTT, (long)NN*HTT, ZT_BF, HTT, (long)NN*HTT, HTT,
        nullptr, CT_BF+po, NN, (long)NN*NN,
        ws+OFF_NT, ws+OFF_NT, nullptr, nullptr, nullptr, nullptr);
    // M (bf16)
    k_mfma<MODE_COST><<<dim3(2,2,NB),256,0,stream>>>(
        ZSP_BF, HTT, (long)NN*HTT, ZT_BF, HTT, (long)NN*HTT, HTT,
        nullptr, M_BF+po, NN, (long)NN*NN,
        ws+OFF_NSP, ws+OFF_NT, nullptr, nullptr, nullptr, nullptr);
  }

  // ---- Part B phase 2: Sinkhorn (both passes, multiplicative, K in LDS) ----
  k_sinkhorn_fused<<<2*NB,1024,SINK_DYN_LDS,stream>>>(
      M_BF, ws+OFF_MU, ws+OFF_NU, GN_BF, acc);

  // ---- Part B phase 3: T = Gn@Ct, struct loss (batched over both passes) ----
  k_mfma<MODE_PLAIN><<<dim3(2,2,2*NB),256,0,stream>>>(
      GN_BF, NN, (long)NN*NN, CT_BF, NN, (long)NN*NN, NN,
      nullptr, T_BF, NN, (long)NN*NN,
      nullptr, nullptr, nullptr, nullptr, nullptr, nullptr);
  k_mfma<MODE_STRUCT><<<dim3(2,2,2*NB),256,0,stream>>>(
      T_BF, NN, (long)NN*NN, GN_BF, NN, (long)NN*NN, NN,
      nullptr, nullptr, NN, (long)NN*NN,
      nullptr, nullptr, nullptr, ws+OFF_CS, ws+OFF_MU, acc);

  k_final<<<1,1,0,stream>>>(acc, (float*)d_out);
}